// Round 2
// baseline (808.400 us; speedup 1.0000x reference)
//
#include <hip/hip_runtime.h>
#include <math.h>

#define NR 36
#define NW 32
#define DD 1024
#define EPSF 1e-8f

// ---------------- Gram: images (G[i][r][r2] upper triangle, imgn clamped) ----------------
__global__ __launch_bounds__(256) void gram_img_kernel(const float* __restrict__ img,
                                                       float* __restrict__ G,
                                                       float* __restrict__ imgn) {
  const int i = blockIdx.x;
  const float* A = img + (size_t)i * NR * DD;
  __shared__ float sA[NR][68];
  float acc[6] = {0.f, 0.f, 0.f, 0.f, 0.f, 0.f};
  for (int k0 = 0; k0 < DD; k0 += 64) {
    for (int s = threadIdx.x; s < NR * 16; s += 256) {
      const int r = s >> 4, kq = s & 15;
      *(float4*)&sA[r][kq * 4] = *(const float4*)(A + r * DD + k0 + kq * 4);
    }
    __syncthreads();
#pragma unroll
    for (int pi = 0; pi < 6; ++pi) {
      const int p = (int)threadIdx.x + pi * 256;
      if (p < NR * NR) {
        const int r = p / NR, r2 = p % NR;
        if (r2 >= r) {
          float a = acc[pi];
#pragma unroll
          for (int k = 0; k < 16; ++k) {
            const float4 va = *(const float4*)&sA[r][k * 4];
            const float4 vb = *(const float4*)&sA[r2][k * 4];
            a = fmaf(va.x, vb.x, a); a = fmaf(va.y, vb.y, a);
            a = fmaf(va.z, vb.z, a); a = fmaf(va.w, vb.w, a);
          }
          acc[pi] = a;
        }
      }
    }
    __syncthreads();
  }
#pragma unroll
  for (int pi = 0; pi < 6; ++pi) {
    const int p = (int)threadIdx.x + pi * 256;
    if (p < NR * NR) {
      const int r = p / NR, r2 = p % NR;
      if (r2 >= r) {
        G[(size_t)i * NR * NR + p] = acc[pi];
        if (r2 == r) imgn[i * NR + r] = fmaxf(sqrtf(acc[pi]), EPSF);
      }
    }
  }
}

// ---------------- Gram: captions ----------------
__global__ __launch_bounds__(256) void gram_cap_kernel(const float* __restrict__ cap,
                                                       float* __restrict__ G,
                                                       float* __restrict__ capn) {
  const int cblk = blockIdx.x;
  const float* A = cap + (size_t)cblk * NW * DD;
  __shared__ float sB[NW][68];
  float acc[4] = {0.f, 0.f, 0.f, 0.f};
  for (int k0 = 0; k0 < DD; k0 += 64) {
    for (int s = threadIdx.x; s < NW * 16; s += 256) {
      const int w = s >> 4, kq = s & 15;
      *(float4*)&sB[w][kq * 4] = *(const float4*)(A + w * DD + k0 + kq * 4);
    }
    __syncthreads();
#pragma unroll
    for (int pi = 0; pi < 4; ++pi) {
      const int p = (int)threadIdx.x + pi * 256;
      const int w = p >> 5, w2 = p & 31;
      if (w2 >= w) {
        float a = acc[pi];
#pragma unroll
        for (int k = 0; k < 16; ++k) {
          const float4 va = *(const float4*)&sB[w][k * 4];
          const float4 vb = *(const float4*)&sB[w2][k * 4];
          a = fmaf(va.x, vb.x, a); a = fmaf(va.y, vb.y, a);
          a = fmaf(va.z, vb.z, a); a = fmaf(va.w, vb.w, a);
        }
        acc[pi] = a;
      }
    }
    __syncthreads();
  }
#pragma unroll
  for (int pi = 0; pi < 4; ++pi) {
    const int p = (int)threadIdx.x + pi * 256;
    const int w = p >> 5, w2 = p & 31;
    if (w2 >= w) {
      G[(size_t)cblk * NW * NW + p] = acc[pi];
      if (w2 == w) capn[cblk * NW + w] = fmaxf(sqrtf(acc[pi]), EPSF);
    }
  }
}

// ---------------- GEMM: S = images_chunk @ captions^T, scattered into C1 and C2 ----------------
// C1[((c*36+r)*IC + il)*32 + w]   (row of S contiguous per (c,i,r))  -> i2t
// C2[((il*32+w)*128 + c)*36 + r]  (col of S contiguous per (i,c,w))  -> t2i
__global__ __launch_bounds__(256) void gemm_kernel(const float* __restrict__ A,
                                                   const float* __restrict__ B,
                                                   float* __restrict__ C1,
                                                   float* __restrict__ C2,
                                                   int Mrows, int IC) {
  __shared__ float sA[16][132];
  __shared__ float sB[16][132];
  const int m0 = blockIdx.x * 128;
  const int n0 = blockIdx.y * 128;
  const int tid = threadIdx.x;
  const int ty = tid >> 4, tx = tid & 15;
  float acc[8][8];
#pragma unroll
  for (int a = 0; a < 8; ++a)
#pragma unroll
    for (int b = 0; b < 8; ++b) acc[a][b] = 0.f;

  for (int k0 = 0; k0 < DD; k0 += 16) {
#pragma unroll
    for (int ld = 0; ld < 2; ++ld) {
      const int s = tid + ld * 256;
      const int m = s >> 2, kq = s & 3;
      float4 v = make_float4(0.f, 0.f, 0.f, 0.f);
      const int gm = m0 + m;
      if (gm < Mrows) v = *(const float4*)(A + (size_t)gm * DD + k0 + kq * 4);
      sA[kq * 4 + 0][m] = v.x; sA[kq * 4 + 1][m] = v.y;
      sA[kq * 4 + 2][m] = v.z; sA[kq * 4 + 3][m] = v.w;
    }
#pragma unroll
    for (int ld = 0; ld < 2; ++ld) {
      const int s = tid + ld * 256;
      const int n = s >> 2, kq = s & 3;
      const float4 v = *(const float4*)(B + (size_t)(n0 + n) * DD + k0 + kq * 4);
      sB[kq * 4 + 0][n] = v.x; sB[kq * 4 + 1][n] = v.y;
      sB[kq * 4 + 2][n] = v.z; sB[kq * 4 + 3][n] = v.w;
    }
    __syncthreads();
#pragma unroll
    for (int kk = 0; kk < 16; ++kk) {
      float av[8], bv[8];
      *(float4*)&av[0] = *(const float4*)&sA[kk][ty * 4];
      *(float4*)&av[4] = *(const float4*)&sA[kk][ty * 4 + 64];
      *(float4*)&bv[0] = *(const float4*)&sB[kk][tx * 4];
      *(float4*)&bv[4] = *(const float4*)&sB[kk][tx * 4 + 64];
#pragma unroll
      for (int mi = 0; mi < 8; ++mi)
#pragma unroll
        for (int ni = 0; ni < 8; ++ni)
          acc[mi][ni] = fmaf(av[mi], bv[ni], acc[mi][ni]);
    }
    __syncthreads();
  }
#pragma unroll
  for (int mi = 0; mi < 8; ++mi) {
    const int m = m0 + ty * 4 + (mi < 4 ? mi : 64 + mi - 4);
    if (m >= Mrows) continue;
    const int il = m / NR, r = m % NR;
#pragma unroll
    for (int ni = 0; ni < 8; ++ni) {
      const int n = n0 + tx * 4 + (ni < 4 ? ni : 64 + ni - 4);
      const int cc = n >> 5, w = n & 31;
      const float v = acc[mi][ni];
      C1[(((size_t)cc * NR + r) * IC + il) * NW + w] = v;
      C2[(((size_t)il * NW + w) * 128 + cc) * NR + r] = v;
    }
  }
}

// ---------------- l2norm denominators of leaky_relu(S) ----------------
__global__ __launch_bounds__(256) void norms_row_kernel(const float* __restrict__ C1,
                                                        float* __restrict__ rown,
                                                        int IC, int total) {
  const int idx = blockIdx.x * 256 + threadIdx.x;
  if (idx >= total) return;
  const int r = idx % NR;
  const int p = idx / NR;         // p = c*IC + il
  const int il = p % IC, c = p / IC;
  const float* row = C1 + (((size_t)c * NR + r) * IC + il) * NW;
  float ssum = 0.f;
#pragma unroll
  for (int j = 0; j < 8; ++j) {
    const float4 v = *(const float4*)(row + 4 * j);
    float a;
    a = v.x > 0.f ? v.x : 0.1f * v.x; ssum = fmaf(a, a, ssum);
    a = v.y > 0.f ? v.y : 0.1f * v.y; ssum = fmaf(a, a, ssum);
    a = v.z > 0.f ? v.z : 0.1f * v.z; ssum = fmaf(a, a, ssum);
    a = v.w > 0.f ? v.w : 0.1f * v.w; ssum = fmaf(a, a, ssum);
  }
  rown[idx] = sqrtf(ssum);
}

__global__ __launch_bounds__(256) void norms_col_kernel(const float* __restrict__ C2,
                                                        float* __restrict__ coln,
                                                        int IC, int total) {
  const int idx = blockIdx.x * 256 + threadIdx.x;
  if (idx >= total) return;
  const int w = idx % NW;
  const int p = idx / NW;         // p = c*IC + il
  const int il = p % IC, c = p / IC;
  const float* col = C2 + (((size_t)il * NW + w) * 128 + c) * NR;
  float ssum = 0.f;
#pragma unroll
  for (int j = 0; j < 9; ++j) {
    const float4 v = *(const float4*)(col + 4 * j);
    float a;
    a = v.x > 0.f ? v.x : 0.1f * v.x; ssum = fmaf(a, a, ssum);
    a = v.y > 0.f ? v.y : 0.1f * v.y; ssum = fmaf(a, a, ssum);
    a = v.z > 0.f ? v.z : 0.1f * v.z; ssum = fmaf(a, a, ssum);
    a = v.w > 0.f ? v.w : 0.1f * v.w; ssum = fmaf(a, a, ssum);
  }
  coln[idx] = sqrtf(ssum);
}

// ---------------- t2i: block=(image il, caption half), lane=caption ----------------
__global__ __launch_bounds__(512) void attn_t2i_kernel(const float* __restrict__ C2,
                                                       const float* __restrict__ Gimg,
                                                       const float* __restrict__ rown,
                                                       const float* __restrict__ capn,
                                                       float* __restrict__ out,
                                                       int IC, int i0) {
  const int il = blockIdx.x;
  const int chalf = blockIdx.y;
  const int lane = threadIdx.x & 63;
  const int wv = threadIdx.x >> 6;
  const int c = chalf * 64 + lane;
  const int ig = i0 + il;
  __shared__ float red[64];
  if (threadIdx.x < 64) red[threadIdx.x] = 0.f;
  __syncthreads();

  float inv[NR];
  {
    const float* rp = rown + ((size_t)c * IC + il) * NR;
#pragma unroll
    for (int j = 0; j < 9; ++j) {
      const float4 v = *(const float4*)(rp + 4 * j);
      inv[4 * j + 0] = 20.f / (v.x + EPSF);
      inv[4 * j + 1] = 20.f / (v.y + EPSF);
      inv[4 * j + 2] = 20.f / (v.z + EPSF);
      inv[4 * j + 3] = 20.f / (v.w + EPSF);
    }
  }
  const float* G = Gimg + (size_t)ig * (NR * NR);
  float acc = 0.f;
  for (int w = wv; w < NW; w += 8) {
    const float* sp = C2 + (((size_t)il * NW + w) * 128 + c) * NR;
    float s[NR], z[NR];
#pragma unroll
    for (int j = 0; j < 9; ++j) {
      const float4 v = *(const float4*)(sp + 4 * j);
      s[4 * j + 0] = v.x; s[4 * j + 1] = v.y; s[4 * j + 2] = v.z; s[4 * j + 3] = v.w;
    }
    float mz = -1e30f;
#pragma unroll
    for (int r = 0; r < NR; ++r) {
      const float L = s[r] > 0.f ? s[r] : 0.1f * s[r];
      z[r] = L * inv[r];
      mz = fmaxf(mz, z[r]);
    }
    float s1 = 0.f;
#pragma unroll
    for (int r = 0; r < NR; ++r) { z[r] = __expf(z[r] - mz); s1 += z[r]; }
    const float thr = s1 * (1.f / NR);
    float num = 0.f;
#pragma unroll
    for (int r = 0; r < NR; ++r) {
      z[r] = (z[r] > thr) ? z[r] : 0.f;   // focal mask; renorm factor cancels
      num = fmaf(z[r], s[r], num);
    }
    float den2 = 0.f;
#pragma unroll
    for (int r = 0; r < NR; ++r) {
      const float t = z[r];
      float h = 0.5f * t * G[r * NR + r];   // G uniform -> scalar loads
#pragma unroll
      for (int r2 = r + 1; r2 < NR; ++r2) h = fmaf(z[r2], G[r * NR + r2], h);
      den2 = fmaf(t, h, den2);
    }
    den2 *= 2.f;
    const float cn = capn[c * NW + w];
    acc += num / (cn * sqrtf(den2) + 1e-30f);
  }
  atomicAdd(&red[lane], acc);
  __syncthreads();
  if (threadIdx.x < 64)
    out[(size_t)ig * 128 + chalf * 64 + threadIdx.x] = red[threadIdx.x] * (1.f / NW);
}

// ---------------- i2t: block=(caption c, image group), lane=image ----------------
__global__ __launch_bounds__(512) void attn_i2t_kernel(const float* __restrict__ C1,
                                                       const float* __restrict__ Gcap,
                                                       const float* __restrict__ coln,
                                                       const float* __restrict__ imgn,
                                                       float* __restrict__ out,
                                                       int IC, int i0) {
  const int c = blockIdx.x;
  const int g = blockIdx.y;
  const int ICb = IC < 64 ? IC : 64;
  const int lsh = 31 - __clz(ICb);        // log2(ICb)
  const int nq = 64 >> lsh;
  const int lane = threadIdx.x & 63;
  const int wv = threadIdx.x >> 6;
  const int il = g * 64 + (lane & (ICb - 1));
  const int q = lane >> lsh;
  const int ig = i0 + il;
  __shared__ float red[64];
  if (threadIdx.x < 64) red[threadIdx.x] = 0.f;
  __syncthreads();

  float inv[NW];
  {
    const float* cp = coln + ((size_t)c * IC + il) * NW;
#pragma unroll
    for (int j = 0; j < 8; ++j) {
      const float4 v = *(const float4*)(cp + 4 * j);
      inv[4 * j + 0] = 20.f / (v.x + EPSF);
      inv[4 * j + 1] = 20.f / (v.y + EPSF);
      inv[4 * j + 2] = 20.f / (v.z + EPSF);
      inv[4 * j + 3] = 20.f / (v.w + EPSF);
    }
  }
  const float* G = Gcap + (size_t)c * (NW * NW);
  float acc = 0.f;
  const int nslots = 8 * nq;
  for (int r = wv * nq + q; r < NR; r += nslots) {
    const float* sp = C1 + (((size_t)c * NR + r) * IC + il) * NW;
    float s[NW], z[NW];
#pragma unroll
    for (int j = 0; j < 8; ++j) {
      const float4 v = *(const float4*)(sp + 4 * j);
      s[4 * j + 0] = v.x; s[4 * j + 1] = v.y; s[4 * j + 2] = v.z; s[4 * j + 3] = v.w;
    }
    float mz = -1e30f;
#pragma unroll
    for (int w = 0; w < NW; ++w) {
      const float L = s[w] > 0.f ? s[w] : 0.1f * s[w];
      z[w] = L * inv[w];
      mz = fmaxf(mz, z[w]);
    }
    float s1 = 0.f;
#pragma unroll
    for (int w = 0; w < NW; ++w) { z[w] = __expf(z[w] - mz); s1 += z[w]; }
    const float thr = s1 * (1.f / NW);
    float num = 0.f;
#pragma unroll
    for (int w = 0; w < NW; ++w) {
      z[w] = (z[w] > thr) ? z[w] : 0.f;
      num = fmaf(z[w], s[w], num);
    }
    float den2 = 0.f;
#pragma unroll
    for (int w = 0; w < NW; ++w) {
      const float t = z[w];
      float h = 0.5f * t * G[w * NW + w];
#pragma unroll
      for (int w2 = w + 1; w2 < NW; ++w2) h = fmaf(z[w2], G[w * NW + w2], h);
      den2 = fmaf(t, h, den2);
    }
    den2 *= 2.f;
    const float inorm = imgn[ig * NR + r];
    acc += num / (inorm * sqrtf(den2) + 1e-30f);
  }
  atomicAdd(&red[lane & (ICb - 1)], acc);
  __syncthreads();
  if ((int)threadIdx.x < ICb)
    out[(size_t)(i0 + g * 64 + threadIdx.x) * 128 + c] += red[threadIdx.x] * (1.f / NR);
}

extern "C" void kernel_launch(void* const* d_in, const int* in_sizes, int n_in,
                              void* d_out, int out_size, void* d_ws, size_t ws_size,
                              hipStream_t stream) {
  (void)in_sizes; (void)n_in; (void)out_size;
  const float* images = (const float*)d_in[0];
  const float* captions = (const float*)d_in[1];
  float* out = (float*)d_out;
  float* ws = (float*)d_ws;

  float* Gimg = ws;                       // 128*1296
  float* Gcap = Gimg + 128 * 1296;        // 128*1024
  float* imgn = Gcap + 128 * 1024;        // 128*36
  float* capn = imgn + 128 * 36;          // 128*32
  float* dyn = capn + 128 * 32;

  const size_t fixedF = (size_t)(128 * 1296 + 128 * 1024 + 128 * 36 + 128 * 32);
  int IC = 1;
  const int cands[8] = {128, 64, 32, 16, 8, 4, 2, 1};
  for (int k = 0; k < 8; ++k) {
    const size_t need = (fixedF + (size_t)cands[k] * (2 * 147456 + 128 * 68)) * sizeof(float);
    if (need <= ws_size) { IC = cands[k]; break; }
  }
  float* rown = dyn;                                 // 128*IC*36
  float* coln = rown + (size_t)128 * IC * NR;        // 128*IC*32
  float* C1 = coln + (size_t)128 * IC * NW;          // IC*147456
  float* C2 = C1 + (size_t)IC * 147456;              // IC*147456

  gram_img_kernel<<<128, 256, 0, stream>>>(images, Gimg, imgn);
  gram_cap_kernel<<<128, 256, 0, stream>>>(captions, Gcap, capn);

  const int nch = 128 / IC;
  const int Mrows = IC * NR;
  const int grid_m = (Mrows + 127) / 128;
  for (int ci = 0; ci < nch; ++ci) {
    const int i0 = ci * IC;
    gemm_kernel<<<dim3(grid_m, 32), 256, 0, stream>>>(
        images + (size_t)i0 * NR * DD, captions, C1, C2, Mrows, IC);
    const int totR = 128 * IC * NR;
    norms_row_kernel<<<(totR + 255) / 256, 256, 0, stream>>>(C1, rown, IC, totR);
    const int totC = 128 * IC * NW;
    norms_col_kernel<<<(totC + 255) / 256, 256, 0, stream>>>(C2, coln, IC, totC);
    attn_t2i_kernel<<<dim3(IC, 2), 512, 0, stream>>>(C2, Gimg, rown, capn, out, IC, i0);
    attn_i2t_kernel<<<dim3(128, (IC >= 64) ? (IC / 64) : 1), 512, 0, stream>>>(
        C1, Gcap, coln, imgn, out, IC, i0);
  }
}

// Round 3
// 470.961 us; speedup vs baseline: 1.7165x; 1.7165x over previous
//
#include <hip/hip_runtime.h>
#include <math.h>

#define NR 36
#define NW 32
#define DD 1024
#define EPSF 1e-8f

typedef _Float16 f16x8 __attribute__((ext_vector_type(8)));
typedef _Float16 f16x4 __attribute__((ext_vector_type(4)));
typedef float f32x16 __attribute__((ext_vector_type(16)));
#define MFMA32(a, b, c) __builtin_amdgcn_mfma_f32_32x32x16_f16((a), (b), (c), 0, 0, 0)

// ---------------- fp32 -> f16 hi/lo split (compensated) ----------------
__global__ __launch_bounds__(256) void split_f16_kernel(const float* __restrict__ src,
                                                        _Float16* __restrict__ hi,
                                                        _Float16* __restrict__ lo, int n4) {
  const int idx = blockIdx.x * 256 + threadIdx.x;
  if (idx >= n4) return;
  const float4 v = *(const float4*)(src + (size_t)idx * 4);
  const _Float16 h0 = (_Float16)v.x, h1 = (_Float16)v.y, h2 = (_Float16)v.z, h3 = (_Float16)v.w;
  f16x4 h = {h0, h1, h2, h3};
  f16x4 l = {(_Float16)(v.x - (float)h0), (_Float16)(v.y - (float)h1),
             (_Float16)(v.z - (float)h2), (_Float16)(v.w - (float)h3)};
  *(f16x4*)(hi + (size_t)idx * 4) = h;
  *(f16x4*)(lo + (size_t)idx * 4) = l;
}

// ---------------- Gram: images, 2x2 register tiling over 18x18 tile grid ----------------
__global__ __launch_bounds__(256) void gram_img_kernel(const float* __restrict__ img,
                                                       float* __restrict__ G,
                                                       float* __restrict__ imgn) {
  const int i = blockIdx.x;
  const float* A = img + (size_t)i * NR * DD;
  __shared__ float sA[NR][68];
  const int t = threadIdx.x;
  int ti = 0, tj = 0;
  const bool active = t < 171;  // 18*19/2 upper-tri 2x2 tiles
  if (active) {
    int rem = t, rowlen = 18;
    while (rem >= rowlen) { rem -= rowlen; ++ti; --rowlen; }
    tj = ti + rem;
  }
  const int a0 = 2 * ti, a1 = 2 * ti + 1, b0 = 2 * tj, b1 = 2 * tj + 1;
  float g00 = 0.f, g01 = 0.f, g10 = 0.f, g11 = 0.f;
  for (int k0 = 0; k0 < DD; k0 += 64) {
    for (int s = t; s < NR * 16; s += 256) {
      const int r = s >> 4, kq = s & 15;
      *(float4*)&sA[r][kq * 4] = *(const float4*)(A + r * DD + k0 + kq * 4);
    }
    __syncthreads();
    if (active) {
#pragma unroll
      for (int k = 0; k < 16; ++k) {
        const float4 va0 = *(const float4*)&sA[a0][k * 4];
        const float4 va1 = *(const float4*)&sA[a1][k * 4];
        const float4 vb0 = *(const float4*)&sA[b0][k * 4];
        const float4 vb1 = *(const float4*)&sA[b1][k * 4];
        g00 = fmaf(va0.x, vb0.x, g00); g00 = fmaf(va0.y, vb0.y, g00);
        g00 = fmaf(va0.z, vb0.z, g00); g00 = fmaf(va0.w, vb0.w, g00);
        g01 = fmaf(va0.x, vb1.x, g01); g01 = fmaf(va0.y, vb1.y, g01);
        g01 = fmaf(va0.z, vb1.z, g01); g01 = fmaf(va0.w, vb1.w, g01);
        g10 = fmaf(va1.x, vb0.x, g10); g10 = fmaf(va1.y, vb0.y, g10);
        g10 = fmaf(va1.z, vb0.z, g10); g10 = fmaf(va1.w, vb0.w, g10);
        g11 = fmaf(va1.x, vb1.x, g11); g11 = fmaf(va1.y, vb1.y, g11);
        g11 = fmaf(va1.z, vb1.z, g11); g11 = fmaf(va1.w, vb1.w, g11);
      }
    }
    __syncthreads();
  }
  if (active) {
    float* Gi = G + (size_t)i * NR * NR;
    Gi[a0 * NR + b0] = g00;
    Gi[a0 * NR + b1] = g01;
    Gi[a1 * NR + b1] = g11;
    if (ti != tj) Gi[a1 * NR + b0] = g10;
    if (ti == tj) {
      imgn[i * NR + a0] = fmaxf(sqrtf(g00), EPSF);
      imgn[i * NR + a1] = fmaxf(sqrtf(g11), EPSF);
    }
  }
}

// ---------------- Gram: captions, 2x2 tiling over 16x16 tile grid ----------------
__global__ __launch_bounds__(256) void gram_cap_kernel(const float* __restrict__ cap,
                                                       float* __restrict__ G,
                                                       float* __restrict__ capn) {
  const int cb = blockIdx.x;
  const float* A = cap + (size_t)cb * NW * DD;
  __shared__ float sB[NW][68];
  const int t = threadIdx.x;
  int ti = 0, tj = 0;
  const bool active = t < 136;  // 16*17/2
  if (active) {
    int rem = t, rowlen = 16;
    while (rem >= rowlen) { rem -= rowlen; ++ti; --rowlen; }
    tj = ti + rem;
  }
  const int a0 = 2 * ti, a1 = 2 * ti + 1, b0 = 2 * tj, b1 = 2 * tj + 1;
  float g00 = 0.f, g01 = 0.f, g10 = 0.f, g11 = 0.f;
  for (int k0 = 0; k0 < DD; k0 += 64) {
    for (int s = t; s < NW * 16; s += 256) {
      const int w = s >> 4, kq = s & 15;
      *(float4*)&sB[w][kq * 4] = *(const float4*)(A + w * DD + k0 + kq * 4);
    }
    __syncthreads();
    if (active) {
#pragma unroll
      for (int k = 0; k < 16; ++k) {
        const float4 va0 = *(const float4*)&sB[a0][k * 4];
        const float4 va1 = *(const float4*)&sB[a1][k * 4];
        const float4 vb0 = *(const float4*)&sB[b0][k * 4];
        const float4 vb1 = *(const float4*)&sB[b1][k * 4];
        g00 = fmaf(va0.x, vb0.x, g00); g00 = fmaf(va0.y, vb0.y, g00);
        g00 = fmaf(va0.z, vb0.z, g00); g00 = fmaf(va0.w, vb0.w, g00);
        g01 = fmaf(va0.x, vb1.x, g01); g01 = fmaf(va0.y, vb1.y, g01);
        g01 = fmaf(va0.z, vb1.z, g01); g01 = fmaf(va0.w, vb1.w, g01);
        g10 = fmaf(va1.x, vb0.x, g10); g10 = fmaf(va1.y, vb0.y, g10);
        g10 = fmaf(va1.z, vb0.z, g10); g10 = fmaf(va1.w, vb0.w, g10);
        g11 = fmaf(va1.x, vb1.x, g11); g11 = fmaf(va1.y, vb1.y, g11);
        g11 = fmaf(va1.z, vb1.z, g11); g11 = fmaf(va1.w, vb1.w, g11);
      }
    }
    __syncthreads();
  }
  if (active) {
    float* Gc = G + (size_t)cb * NW * NW;
    Gc[a0 * NW + b0] = g00;
    Gc[a0 * NW + b1] = g01;
    Gc[a1 * NW + b1] = g11;
    if (ti != tj) Gc[a1 * NW + b0] = g10;
    if (ti == tj) {
      capn[cb * NW + a0] = fmaxf(sqrtf(g00), EPSF);
      capn[cb * NW + a1] = fmaxf(sqrtf(g11), EPSF);
    }
  }
}

// ---------------- MFMA GEMM: S = A @ B^T via f16 split (Ah*Bh + Ah*Bl + Al*Bh) ----------------
// 128x128 tile, BK=32, 256 thr (4 waves, each 64x64 = 2x2 mfma_32x32x16 tiles).
// C1[((c*36+r)*IC + il)*32 + w]  -> i2t ;  C2[((il*32+w)*128 + c)*36 + r] -> t2i
__global__ __launch_bounds__(256) void mfma_gemm_kernel(
    const _Float16* __restrict__ Ah, const _Float16* __restrict__ Al,
    const _Float16* __restrict__ Bh, const _Float16* __restrict__ Bl,
    float* __restrict__ C1, float* __restrict__ C2, int Mrows, int IC) {
  constexpr int LDH = 40;            // 32 + 8 pad halves (16B-aligned rows)
  constexpr int PLANE = 128 * LDH;   // halves per plane
  __shared__ _Float16 lds[4 * PLANE];
  const int tid = threadIdx.x;
  const int m0 = blockIdx.x * 128, n0 = blockIdx.y * 128;

  // ---- staging assignment: plane p = tid>>6, 64 threads per plane ----
  const int p = tid >> 6, t6 = tid & 63;
  const bool isA = p < 2;
  const _Float16* gsrc = (p == 0) ? Ah : (p == 1) ? Al : (p == 2) ? Bh : Bl;
  const int rowbase = isA ? m0 : n0;
  const int r0 = t6 >> 2, cq = t6 & 3;
  const _Float16* g = gsrc + (size_t)(rowbase + r0) * DD + cq * 8;
  const int lw = p * PLANE + r0 * LDH + cq * 8;

  // ---- fragment addressing ----
  const int lane = tid & 63, wv = tid >> 6;
  const int mh = wv >> 1, nh = wv & 1;
  const int lm = lane & 31, kb = lane >> 5;
  const int ra0 = (mh * 64 + lm) * LDH + kb * 8;
  const int ra1 = ra0 + 32 * LDH;
  const int rb0 = 2 * PLANE + (nh * 64 + lm) * LDH + kb * 8;
  const int rb1 = rb0 + 32 * LDH;

  f32x16 acc00 = {}, acc01 = {}, acc10 = {}, acc11 = {};
  f16x8 st[8];
#pragma unroll
  for (int i = 0; i < 8; ++i) {
    f16x8 v = {};
    if (!isA || (rowbase + r0 + i * 16) < Mrows) v = *(const f16x8*)(g + (size_t)i * 16 * DD);
    st[i] = v;
  }
  for (int kt = 0; kt < DD / 32; ++kt) {
    __syncthreads();
#pragma unroll
    for (int i = 0; i < 8; ++i) *(f16x8*)&lds[lw + i * 16 * LDH] = st[i];
    __syncthreads();
    if (kt < DD / 32 - 1) {
      const _Float16* gk = g + (kt + 1) * 32;
#pragma unroll
      for (int i = 0; i < 8; ++i) {
        f16x8 v = {};
        if (!isA || (rowbase + r0 + i * 16) < Mrows) v = *(const f16x8*)(gk + (size_t)i * 16 * DD);
        st[i] = v;
      }
    }
#pragma unroll
    for (int s = 0; s < 32; s += 16) {
      const f16x8 ah0 = *(const f16x8*)&lds[ra0 + s];
      const f16x8 ah1 = *(const f16x8*)&lds[ra1 + s];
      const f16x8 alo0 = *(const f16x8*)&lds[PLANE + ra0 + s];
      const f16x8 alo1 = *(const f16x8*)&lds[PLANE + ra1 + s];
      const f16x8 bh0 = *(const f16x8*)&lds[rb0 + s];
      const f16x8 bh1 = *(const f16x8*)&lds[rb1 + s];
      const f16x8 blo0 = *(const f16x8*)&lds[PLANE + rb0 + s];
      const f16x8 blo1 = *(const f16x8*)&lds[PLANE + rb1 + s];
      acc00 = MFMA32(ah0, bh0, acc00);
      acc01 = MFMA32(ah0, bh1, acc01);
      acc10 = MFMA32(ah1, bh0, acc10);
      acc11 = MFMA32(ah1, bh1, acc11);
      acc00 = MFMA32(ah0, blo0, acc00);
      acc01 = MFMA32(ah0, blo1, acc01);
      acc10 = MFMA32(ah1, blo0, acc10);
      acc11 = MFMA32(ah1, blo1, acc11);
      acc00 = MFMA32(alo0, bh0, acc00);
      acc01 = MFMA32(alo0, bh1, acc01);
      acc10 = MFMA32(alo1, bh0, acc10);
      acc11 = MFMA32(alo1, bh1, acc11);
    }
  }
  // ---- epilogue: C/D layout col=lane&31, row=(q&3)+8*(q>>2)+4*(lane>>5) ----
#pragma unroll
  for (int i = 0; i < 2; ++i)
#pragma unroll
    for (int j = 0; j < 2; ++j) {
      const f32x16 a = (i == 0) ? (j == 0 ? acc00 : acc01) : (j == 0 ? acc10 : acc11);
      const int col = n0 + nh * 64 + j * 32 + lm;
      const int c = col >> 5, w = col & 31;
#pragma unroll
      for (int q = 0; q < 16; ++q) {
        const int row32 = (q & 3) + 8 * (q >> 2) + 4 * kb;
        const int m = m0 + mh * 64 + i * 32 + row32;
        if (m < Mrows) {
          const int il = m / NR, r = m - il * NR;
          const float v = a[q];
          C1[(((size_t)c * NR + r) * IC + il) * NW + w] = v;
          C2[(((size_t)il * NW + w) * 128 + c) * NR + r] = v;
        }
      }
    }
}

// ---------------- l2norm denominators of leaky_relu(S) ----------------
__global__ __launch_bounds__(256) void norms_row_kernel(const float* __restrict__ C1,
                                                        float* __restrict__ rown,
                                                        int IC, int total) {
  const int idx = blockIdx.x * 256 + threadIdx.x;
  if (idx >= total) return;
  const int r = idx % NR;
  const int p = idx / NR;  // p = c*IC + il
  const int il = p % IC, c = p / IC;
  const float* row = C1 + (((size_t)c * NR + r) * IC + il) * NW;
  float ssum = 0.f;
#pragma unroll
  for (int j = 0; j < 8; ++j) {
    const float4 v = *(const float4*)(row + 4 * j);
    float a;
    a = v.x > 0.f ? v.x : 0.1f * v.x; ssum = fmaf(a, a, ssum);
    a = v.y > 0.f ? v.y : 0.1f * v.y; ssum = fmaf(a, a, ssum);
    a = v.z > 0.f ? v.z : 0.1f * v.z; ssum = fmaf(a, a, ssum);
    a = v.w > 0.f ? v.w : 0.1f * v.w; ssum = fmaf(a, a, ssum);
  }
  rown[idx] = sqrtf(ssum);
}

__global__ __launch_bounds__(256) void norms_col_kernel(const float* __restrict__ C2,
                                                        float* __restrict__ coln,
                                                        int IC, int total) {
  const int idx = blockIdx.x * 256 + threadIdx.x;
  if (idx >= total) return;
  const int w = idx % NW;
  const int p = idx / NW;  // p = c*IC + il
  const int il = p % IC, c = p / IC;
  const float* col = C2 + (((size_t)il * NW + w) * 128 + c) * NR;
  float ssum = 0.f;
#pragma unroll
  for (int j = 0; j < 9; ++j) {
    const float4 v = *(const float4*)(col + 4 * j);
    float a;
    a = v.x > 0.f ? v.x : 0.1f * v.x; ssum = fmaf(a, a, ssum);
    a = v.y > 0.f ? v.y : 0.1f * v.y; ssum = fmaf(a, a, ssum);
    a = v.z > 0.f ? v.z : 0.1f * v.z; ssum = fmaf(a, a, ssum);
    a = v.w > 0.f ? v.w : 0.1f * v.w; ssum = fmaf(a, a, ssum);
  }
  coln[idx] = sqrtf(ssum);
}

// ---------------- t2i: block=(image il, caption half), lane=caption ----------------
__global__ __launch_bounds__(512) void attn_t2i_kernel(const float* __restrict__ C2,
                                                       const float* __restrict__ Gimg,
                                                       const float* __restrict__ rown,
                                                       const float* __restrict__ capn,
                                                       float* __restrict__ out,
                                                       int IC, int i0) {
  const int il = blockIdx.x;
  const int chalf = blockIdx.y;
  const int lane = threadIdx.x & 63;
  const int wv = threadIdx.x >> 6;
  const int c = chalf * 64 + lane;
  const int ig = i0 + il;
  __shared__ float red[64];
  if (threadIdx.x < 64) red[threadIdx.x] = 0.f;
  __syncthreads();

  float inv[NR];
  {
    const float* rp = rown + ((size_t)c * IC + il) * NR;
#pragma unroll
    for (int j = 0; j < 9; ++j) {
      const float4 v = *(const float4*)(rp + 4 * j);
      inv[4 * j + 0] = 20.f / (v.x + EPSF);
      inv[4 * j + 1] = 20.f / (v.y + EPSF);
      inv[4 * j + 2] = 20.f / (v.z + EPSF);
      inv[4 * j + 3] = 20.f / (v.w + EPSF);
    }
  }
  const float* G = Gimg + (size_t)ig * (NR * NR);
  float acc = 0.f;
  for (int w = wv; w < NW; w += 8) {
    const float* sp = C2 + (((size_t)il * NW + w) * 128 + c) * NR;
    float s[NR], z[NR];
#pragma unroll
    for (int j = 0; j < 9; ++j) {
      const float4 v = *(const float4*)(sp + 4 * j);
      s[4 * j + 0] = v.x; s[4 * j + 1] = v.y; s[4 * j + 2] = v.z; s[4 * j + 3] = v.w;
    }
    float mz = -1e30f;
#pragma unroll
    for (int r = 0; r < NR; ++r) {
      const float L = s[r] > 0.f ? s[r] : 0.1f * s[r];
      z[r] = L * inv[r];
      mz = fmaxf(mz, z[r]);
    }
    float s1 = 0.f;
#pragma unroll
    for (int r = 0; r < NR; ++r) { z[r] = __expf(z[r] - mz); s1 += z[r]; }
    const float thr = s1 * (1.f / NR);
    float num = 0.f;
#pragma unroll
    for (int r = 0; r < NR; ++r) {
      z[r] = (z[r] > thr) ? z[r] : 0.f;  // focal mask; renorm cancels
      num = fmaf(z[r], s[r], num);
    }
    float den2 = 0.f;
#pragma unroll
    for (int r = 0; r < NR; ++r) {
      const float t = z[r];
      float h = 0.5f * t * G[r * NR + r];
#pragma unroll
      for (int r2 = r + 1; r2 < NR; ++r2) h = fmaf(z[r2], G[r * NR + r2], h);
      den2 = fmaf(t, h, den2);
    }
    den2 *= 2.f;
    const float cn = capn[c * NW + w];
    acc += num / (cn * sqrtf(den2) + 1e-30f);
  }
  atomicAdd(&red[lane], acc);
  __syncthreads();
  if (threadIdx.x < 64)
    out[(size_t)ig * 128 + chalf * 64 + threadIdx.x] = red[threadIdx.x] * (1.f / NW);
}

// ---------------- i2t: block=(caption c, image group), lane=image ----------------
__global__ __launch_bounds__(512) void attn_i2t_kernel(const float* __restrict__ C1,
                                                       const float* __restrict__ Gcap,
                                                       const float* __restrict__ coln,
                                                       const float* __restrict__ imgn,
                                                       float* __restrict__ out,
                                                       int IC, int i0) {
  const int c = blockIdx.x;
  const int g = blockIdx.y;
  const int ICb = IC < 64 ? IC : 64;
  const int lsh = 31 - __clz(ICb);
  const int nq = 64 >> lsh;
  const int lane = threadIdx.x & 63;
  const int wv = threadIdx.x >> 6;
  const int il = g * 64 + (lane & (ICb - 1));
  const int q = lane >> lsh;
  const int ig = i0 + il;
  __shared__ float red[64];
  if (threadIdx.x < 64) red[threadIdx.x] = 0.f;
  __syncthreads();

  float inv[NW];
  {
    const float* cp = coln + ((size_t)c * IC + il) * NW;
#pragma unroll
    for (int j = 0; j < 8; ++j) {
      const float4 v = *(const float4*)(cp + 4 * j);
      inv[4 * j + 0] = 20.f / (v.x + EPSF);
      inv[4 * j + 1] = 20.f / (v.y + EPSF);
      inv[4 * j + 2] = 20.f / (v.z + EPSF);
      inv[4 * j + 3] = 20.f / (v.w + EPSF);
    }
  }
  const float* G = Gcap + (size_t)c * (NW * NW);
  float acc = 0.f;
  const int nslots = 8 * nq;
  for (int r = wv * nq + q; r < NR; r += nslots) {
    const float* sp = C1 + (((size_t)c * NR + r) * IC + il) * NW;
    float s[NW], z[NW];
#pragma unroll
    for (int j = 0; j < 8; ++j) {
      const float4 v = *(const float4*)(sp + 4 * j);
      s[4 * j + 0] = v.x; s[4 * j + 1] = v.y; s[4 * j + 2] = v.z; s[4 * j + 3] = v.w;
    }
    float mz = -1e30f;
#pragma unroll
    for (int w = 0; w < NW; ++w) {
      const float L = s[w] > 0.f ? s[w] : 0.1f * s[w];
      z[w] = L * inv[w];
      mz = fmaxf(mz, z[w]);
    }
    float s1 = 0.f;
#pragma unroll
    for (int w = 0; w < NW; ++w) { z[w] = __expf(z[w] - mz); s1 += z[w]; }
    const float thr = s1 * (1.f / NW);
    float num = 0.f;
#pragma unroll
    for (int w = 0; w < NW; ++w) {
      z[w] = (z[w] > thr) ? z[w] : 0.f;
      num = fmaf(z[w], s[w], num);
    }
    float den2 = 0.f;
#pragma unroll
    for (int w = 0; w < NW; ++w) {
      const float t = z[w];
      float h = 0.5f * t * G[w * NW + w];
#pragma unroll
      for (int w2 = w + 1; w2 < NW; ++w2) h = fmaf(z[w2], G[w * NW + w2], h);
      den2 = fmaf(t, h, den2);
    }
    den2 *= 2.f;
    const float inorm = imgn[ig * NR + r];
    acc += num / (inorm * sqrtf(den2) + 1e-30f);
  }
  atomicAdd(&red[lane & (ICb - 1)], acc);
  __syncthreads();
  if ((int)threadIdx.x < ICb)
    out[(size_t)(i0 + g * 64 + threadIdx.x) * 128 + c] += red[threadIdx.x] * (1.f / NR);
}

extern "C" void kernel_launch(void* const* d_in, const int* in_sizes, int n_in,
                              void* d_out, int out_size, void* d_ws, size_t ws_size,
                              hipStream_t stream) {
  (void)in_sizes; (void)n_in; (void)out_size;
  const float* images = (const float*)d_in[0];
  const float* captions = (const float*)d_in[1];
  float* out = (float*)d_out;

  char* wb = (char*)d_ws;
  _Float16* Bh = (_Float16*)wb; wb += (size_t)4096 * 1024 * 2;
  _Float16* Bl = (_Float16*)wb; wb += (size_t)4096 * 1024 * 2;
  float* Gimg = (float*)wb; wb += (size_t)128 * 1296 * 4;
  float* Gcap = (float*)wb; wb += (size_t)128 * 1024 * 4;
  float* imgn = (float*)wb; wb += (size_t)128 * 36 * 4;
  float* capn = (float*)wb; wb += (size_t)128 * 32 * 4;
  const size_t fixedB = (size_t)(wb - (char*)d_ws);

  // per-image dynamic bytes: A hi/lo planes + rown/coln + C1 + C2
  const size_t perImg = (size_t)2 * 36 * 1024 * 2 + (size_t)128 * 68 * 4 + (size_t)2 * 589824;
  int IC = 1;
  const int cands[8] = {128, 64, 32, 16, 8, 4, 2, 1};
  for (int k = 0; k < 8; ++k) {
    if (fixedB + (size_t)cands[k] * perImg <= ws_size) { IC = cands[k]; break; }
  }
  _Float16* Ah = (_Float16*)wb; wb += (size_t)IC * 36 * 1024 * 2;
  _Float16* Al = (_Float16*)wb; wb += (size_t)IC * 36 * 1024 * 2;
  float* rown = (float*)wb; wb += (size_t)128 * IC * NR * 4;
  float* coln = (float*)wb; wb += (size_t)128 * IC * NW * 4;
  float* C1 = (float*)wb; wb += (size_t)IC * 147456 * 4;
  float* C2 = (float*)wb;

  gram_img_kernel<<<128, 256, 0, stream>>>(images, Gimg, imgn);
  gram_cap_kernel<<<128, 256, 0, stream>>>(captions, Gcap, capn);
  split_f16_kernel<<<4096, 256, 0, stream>>>(captions, Bh, Bl, 4096 * 1024 / 4);

  const int nch = 128 / IC;
  const int Mrows = IC * NR;
  const int grid_m = (Mrows + 127) / 128;
  for (int ci = 0; ci < nch; ++ci) {
    const int i0 = ci * IC;
    const int n4A = IC * 36 * 1024 / 4;
    split_f16_kernel<<<(n4A + 255) / 256, 256, 0, stream>>>(
        images + (size_t)i0 * NR * DD, Ah, Al, n4A);
    mfma_gemm_kernel<<<dim3(grid_m, 32), 256, 0, stream>>>(Ah, Al, Bh, Bl, C1, C2, Mrows, IC);
    const int totR = 128 * IC * NR;
    norms_row_kernel<<<(totR + 255) / 256, 256, 0, stream>>>(C1, rown, IC, totR);
    const int totC = 128 * IC * NW;
    norms_col_kernel<<<(totC + 255) / 256, 256, 0, stream>>>(C2, coln, IC, totC);
    attn_t2i_kernel<<<dim3(IC, 2), 512, 0, stream>>>(C2, Gimg, rown, capn, out, IC, i0);
    attn_i2t_kernel<<<dim3(128, (IC >= 64) ? (IC / 64) : 1), 512, 0, stream>>>(
        C1, Gcap, coln, imgn, out, IC, i0);
  }
}

// Round 4
// 401.212 us; speedup vs baseline: 2.0149x; 1.1738x over previous
//
#include <hip/hip_runtime.h>
#include <math.h>

#define NR 36
#define NW 32
#define DD 1024
#define EPSF 1e-8f

typedef _Float16 f16x8 __attribute__((ext_vector_type(8)));
typedef _Float16 f16x4 __attribute__((ext_vector_type(4)));
typedef float f32x16 __attribute__((ext_vector_type(16)));
#define MFMA32(a, b, c) __builtin_amdgcn_mfma_f32_32x32x16_f16((a), (b), (c), 0, 0, 0)

__device__ __forceinline__ float leakyf(float x) { return x > 0.f ? x : 0.1f * x; }

// ---------------- fp32 -> f16 hi/lo split, linear layout (for A = images) ----------------
__global__ __launch_bounds__(256) void split_f16_kernel(const float* __restrict__ src,
                                                        _Float16* __restrict__ hi,
                                                        _Float16* __restrict__ lo, int n4) {
  const int idx = blockIdx.x * 256 + threadIdx.x;
  if (idx >= n4) return;
  const float4 v = *(const float4*)(src + (size_t)idx * 4);
  const _Float16 h0 = (_Float16)v.x, h1 = (_Float16)v.y, h2 = (_Float16)v.z, h3 = (_Float16)v.w;
  f16x4 h = {h0, h1, h2, h3};
  f16x4 l = {(_Float16)(v.x - (float)h0), (_Float16)(v.y - (float)h1),
             (_Float16)(v.z - (float)h2), (_Float16)(v.w - (float)h3)};
  *(f16x4*)(hi + (size_t)idx * 4) = h;
  *(f16x4*)(lo + (size_t)idx * 4) = l;
}

// ---------------- fp32 -> f16 hi/lo split, MFMA-fragment layout (for B = captions) -------
// B'[(nb*128 + kq)*32 + lm] (f16x8 units): element n = nb*32+lm, k = kq*8+j
__global__ __launch_bounds__(256) void split_b_kernel(const float* __restrict__ cap,
                                                      _Float16* __restrict__ Bh,
                                                      _Float16* __restrict__ Bl) {
  const int idx = blockIdx.x * 256 + threadIdx.x;  // < 128*128*32 = 524288
  const int lm = idx & 31;
  const int kq = (idx >> 5) & 127;
  const int nb = idx >> 12;
  const float* src = cap + (size_t)(nb * 32 + lm) * DD + kq * 8;
  const float4 v0 = *(const float4*)src;
  const float4 v1 = *(const float4*)(src + 4);
  f16x8 h, l;
  const float a[8] = {v0.x, v0.y, v0.z, v0.w, v1.x, v1.y, v1.z, v1.w};
#pragma unroll
  for (int j = 0; j < 8; ++j) {
    const _Float16 hh = (_Float16)a[j];
    h[j] = hh;
    l[j] = (_Float16)(a[j] - (float)hh);
  }
  *(f16x8*)(Bh + (size_t)idx * 8) = h;
  *(f16x8*)(Bl + (size_t)idx * 8) = l;
}

// ---------------- Gram: images, 2x2 register tiling over 18x18 tile grid ----------------
__global__ __launch_bounds__(256) void gram_img_kernel(const float* __restrict__ img,
                                                       float* __restrict__ G,
                                                       float* __restrict__ imgn) {
  const int i = blockIdx.x;
  const float* A = img + (size_t)i * NR * DD;
  __shared__ float sA[NR][68];
  const int t = threadIdx.x;
  int ti = 0, tj = 0;
  const bool active = t < 171;
  if (active) {
    int rem = t, rowlen = 18;
    while (rem >= rowlen) { rem -= rowlen; ++ti; --rowlen; }
    tj = ti + rem;
  }
  const int a0 = 2 * ti, a1 = 2 * ti + 1, b0 = 2 * tj, b1 = 2 * tj + 1;
  float g00 = 0.f, g01 = 0.f, g10 = 0.f, g11 = 0.f;
  for (int k0 = 0; k0 < DD; k0 += 64) {
    for (int s = t; s < NR * 16; s += 256) {
      const int r = s >> 4, kq = s & 15;
      *(float4*)&sA[r][kq * 4] = *(const float4*)(A + r * DD + k0 + kq * 4);
    }
    __syncthreads();
    if (active) {
#pragma unroll
      for (int k = 0; k < 16; ++k) {
        const float4 va0 = *(const float4*)&sA[a0][k * 4];
        const float4 va1 = *(const float4*)&sA[a1][k * 4];
        const float4 vb0 = *(const float4*)&sA[b0][k * 4];
        const float4 vb1 = *(const float4*)&sA[b1][k * 4];
        g00 = fmaf(va0.x, vb0.x, g00); g00 = fmaf(va0.y, vb0.y, g00);
        g00 = fmaf(va0.z, vb0.z, g00); g00 = fmaf(va0.w, vb0.w, g00);
        g01 = fmaf(va0.x, vb1.x, g01); g01 = fmaf(va0.y, vb1.y, g01);
        g01 = fmaf(va0.z, vb1.z, g01); g01 = fmaf(va0.w, vb1.w, g01);
        g10 = fmaf(va1.x, vb0.x, g10); g10 = fmaf(va1.y, vb0.y, g10);
        g10 = fmaf(va1.z, vb0.z, g10); g10 = fmaf(va1.w, vb0.w, g10);
        g11 = fmaf(va1.x, vb1.x, g11); g11 = fmaf(va1.y, vb1.y, g11);
        g11 = fmaf(va1.z, vb1.z, g11); g11 = fmaf(va1.w, vb1.w, g11);
      }
    }
    __syncthreads();
  }
  if (active) {
    float* Gi = G + (size_t)i * NR * NR;
    Gi[a0 * NR + b0] = g00;
    Gi[a0 * NR + b1] = g01;
    Gi[a1 * NR + b1] = g11;
    if (ti != tj) Gi[a1 * NR + b0] = g10;
    if (ti == tj) {
      imgn[i * NR + a0] = fmaxf(sqrtf(g00), EPSF);
      imgn[i * NR + a1] = fmaxf(sqrtf(g11), EPSF);
    }
  }
}

// ---------------- Gram: captions, 2x2 tiling over 16x16 tile grid ----------------
__global__ __launch_bounds__(256) void gram_cap_kernel(const float* __restrict__ cap,
                                                       float* __restrict__ G,
                                                       float* __restrict__ capn) {
  const int cb = blockIdx.x;
  const float* A = cap + (size_t)cb * NW * DD;
  __shared__ float sB[NW][68];
  const int t = threadIdx.x;
  int ti = 0, tj = 0;
  const bool active = t < 136;
  if (active) {
    int rem = t, rowlen = 16;
    while (rem >= rowlen) { rem -= rowlen; ++ti; --rowlen; }
    tj = ti + rem;
  }
  const int a0 = 2 * ti, a1 = 2 * ti + 1, b0 = 2 * tj, b1 = 2 * tj + 1;
  float g00 = 0.f, g01 = 0.f, g10 = 0.f, g11 = 0.f;
  for (int k0 = 0; k0 < DD; k0 += 64) {
    for (int s = t; s < NW * 16; s += 256) {
      const int w = s >> 4, kq = s & 15;
      *(float4*)&sB[w][kq * 4] = *(const float4*)(A + w * DD + k0 + kq * 4);
    }
    __syncthreads();
    if (active) {
#pragma unroll
      for (int k = 0; k < 16; ++k) {
        const float4 va0 = *(const float4*)&sB[a0][k * 4];
        const float4 va1 = *(const float4*)&sB[a1][k * 4];
        const float4 vb0 = *(const float4*)&sB[b0][k * 4];
        const float4 vb1 = *(const float4*)&sB[b1][k * 4];
        g00 = fmaf(va0.x, vb0.x, g00); g00 = fmaf(va0.y, vb0.y, g00);
        g00 = fmaf(va0.z, vb0.z, g00); g00 = fmaf(va0.w, vb0.w, g00);
        g01 = fmaf(va0.x, vb1.x, g01); g01 = fmaf(va0.y, vb1.y, g01);
        g01 = fmaf(va0.z, vb1.z, g01); g01 = fmaf(va0.w, vb1.w, g01);
        g10 = fmaf(va1.x, vb0.x, g10); g10 = fmaf(va1.y, vb0.y, g10);
        g10 = fmaf(va1.z, vb0.z, g10); g10 = fmaf(va1.w, vb0.w, g10);
        g11 = fmaf(va1.x, vb1.x, g11); g11 = fmaf(va1.y, vb1.y, g11);
        g11 = fmaf(va1.z, vb1.z, g11); g11 = fmaf(va1.w, vb1.w, g11);
      }
    }
    __syncthreads();
  }
  if (active) {
    float* Gc = G + (size_t)cb * NW * NW;
    Gc[a0 * NW + b0] = g00;
    Gc[a0 * NW + b1] = g01;
    Gc[a1 * NW + b1] = g11;
    if (ti != tj) Gc[a1 * NW + b0] = g10;
    if (ti == tj) {
      capn[cb * NW + a0] = fmaxf(sqrtf(g00), EPSF);
      capn[cb * NW + a1] = fmaxf(sqrtf(g11), EPSF);
    }
  }
}

// ---------------- MFMA GEMM: A via global_load_lds (swizzled), B direct from frag layout --
// 128-thr block (2 waves), block tile 128x128, wave tile 64x128 (2 m-tiles x 4 n-tiles).
// C[((i*128 + c)*36 + r)*32 + w]
__global__ __launch_bounds__(128) void mfma_gemm_kernel(
    const _Float16* __restrict__ Ah, const _Float16* __restrict__ Al,
    const _Float16* __restrict__ Bh, const _Float16* __restrict__ Bl,
    float* __restrict__ C) {
  __shared__ _Float16 sA[2 * 128 * 32];  // [plane][row][32 halves], unpadded, XOR-swizzled
  const int tid = threadIdx.x;
  const int m0 = blockIdx.x * 128;
  const int n0b = blockIdx.y * 4;  // B tile-block base (nb)
  const int wv_u = __builtin_amdgcn_readfirstlane(tid >> 6);
  const int lane = tid & 63;
  const int lm = lane & 31, kb = lane >> 5;
  const _Float16* Apl = wv_u ? Al : Ah;   // wave 0 stages hi plane, wave 1 lo plane
  const int srow_l = lane >> 2;           // staging: row within 16-row group
  const int sc = lane & 3;                // staging: dest chunk
  const int rowa0 = wv_u * 64 + lm;       // frag rows for this wave's tiles
  const int rowa1 = rowa0 + 32;
  const int fsw = (lm >> 3) & 3;          // read swizzle (same for both tiles)

  f32x16 acc[2][4];
#pragma unroll
  for (int a = 0; a < 2; ++a)
#pragma unroll
    for (int b = 0; b < 4; ++b) acc[a][b] = {};

  for (int kt = 0; kt < 32; ++kt) {
    // --- B fragment loads for the whole kt (direct global, frag layout) ---
    f16x8 bhf[2][4], blf[2][4];
#pragma unroll
    for (int ks = 0; ks < 2; ++ks)
#pragma unroll
      for (int nt = 0; nt < 4; ++nt) {
        const int kq = kt * 4 + ks * 2 + kb;
        const size_t ofs = ((size_t)((n0b + nt) * 128 + kq) * 32 + lm) * 8;
        bhf[ks][nt] = *(const f16x8*)(Bh + ofs);
        blf[ks][nt] = *(const f16x8*)(Bl + ofs);
      }
    __syncthreads();
    // --- A staging: 8 x global_load_lds (1 KB each) per wave, source-side swizzle ---
#pragma unroll
    for (int u = 0; u < 8; ++u) {
      const int rb = u * 16;
      const int row = rb + srow_l;
      const int kqs = sc ^ ((row >> 3) & 3);
      const _Float16* g = Apl + (size_t)(m0 + row) * DD + kt * 32 + kqs * 8;
      _Float16* lp = &sA[(wv_u * 128 + rb) * 32];
      __builtin_amdgcn_global_load_lds((const __attribute__((address_space(1))) void*)g,
                                       (__attribute__((address_space(3))) void*)lp, 16, 0, 0);
    }
    __syncthreads();  // compiler drains vmcnt here: A in LDS, B frags in regs
    // --- compute ---
#pragma unroll
    for (int ks = 0; ks < 2; ++ks) {
      const int cq = (ks * 2 + kb) ^ fsw;
      const f16x8 ah0 = *(const f16x8*)&sA[(0 * 128 + rowa0) * 32 + cq * 8];
      const f16x8 ah1 = *(const f16x8*)&sA[(0 * 128 + rowa1) * 32 + cq * 8];
      const f16x8 al0 = *(const f16x8*)&sA[(1 * 128 + rowa0) * 32 + cq * 8];
      const f16x8 al1 = *(const f16x8*)&sA[(1 * 128 + rowa1) * 32 + cq * 8];
#pragma unroll
      for (int nt = 0; nt < 4; ++nt) {
        acc[0][nt] = MFMA32(ah0, bhf[ks][nt], acc[0][nt]);
        acc[1][nt] = MFMA32(ah1, bhf[ks][nt], acc[1][nt]);
        acc[0][nt] = MFMA32(ah0, blf[ks][nt], acc[0][nt]);
        acc[1][nt] = MFMA32(ah1, blf[ks][nt], acc[1][nt]);
        acc[0][nt] = MFMA32(al0, bhf[ks][nt], acc[0][nt]);
        acc[1][nt] = MFMA32(al1, bhf[ks][nt], acc[1][nt]);
      }
    }
  }
  // --- epilogue: C/D layout col=lane&31, row=(q&3)+8*(q>>2)+4*(lane>>5) ---
#pragma unroll
  for (int t = 0; t < 2; ++t)
#pragma unroll
    for (int nt = 0; nt < 4; ++nt) {
      const int cc = n0b + nt;  // caption index, w = lm
      const f32x16 a = acc[t][nt];
#pragma unroll
      for (int q = 0; q < 16; ++q) {
        const int row32 = (q & 3) + 8 * (q >> 2) + 4 * kb;
        const int m = m0 + wv_u * 64 + t * 32 + row32;
        const int il = m / NR, r = m - il * NR;
        C[((size_t)il * 128 + cc) * (NR * NW) + r * NW + lm] = a[q];
      }
    }
}

// ---------------- fused post-GEMM: norms + both focal attentions + cosines ----------------
// one wave per (image i, caption c) pair; block = 4 waves = 4 captions.
__global__ __launch_bounds__(256) void fused_attn_kernel(
    const float* __restrict__ C, const float* __restrict__ Gimg, const float* __restrict__ Gcap,
    const float* __restrict__ imgn, const float* __restrict__ capn, float* __restrict__ out) {
  const int i = blockIdx.x;
  const int cg = blockIdx.y;
  const int wv = threadIdx.x >> 6, lane = threadIdx.x & 63;
  const int c = cg * 4 + wv;
  __shared__ float sS[4][NR * NR];  // per wave: S row r at stride 36 (cols w 0..31)
  __shared__ float sInvR[4][NR];
  __shared__ float sInvC[4][NW];
  const float* Cp = C + ((size_t)i * 128 + c) * (NR * NW);
  float srow[NW];
  // ---- phase A: lane r<36 loads its S row, computes row norm (over w) ----
  if (lane < NR) {
    const float* rp = Cp + lane * NW;
#pragma unroll
    for (int j = 0; j < 8; ++j) {
      const float4 v = *(const float4*)(rp + 4 * j);
      srow[4 * j + 0] = v.x; srow[4 * j + 1] = v.y;
      srow[4 * j + 2] = v.z; srow[4 * j + 3] = v.w;
      *(float4*)&sS[wv][lane * NR + 4 * j] = v;
    }
    float rn = 0.f;
#pragma unroll
    for (int w = 0; w < NW; ++w) { const float l = leakyf(srow[w]); rn = fmaf(l, l, rn); }
    sInvR[wv][lane] = 20.f / (sqrtf(rn) + EPSF);
  }
  __syncthreads();
  // ---- phase B: t2i, lane = caption word w < 32 ----
  float t2i_task = 0.f;
  if (lane < NW) {
    float s[NR], z[NR];
    float cn = 0.f;
#pragma unroll
    for (int j = 0; j < NR; ++j) {
      s[j] = sS[wv][j * NR + lane];
      const float l = leakyf(s[j]);
      cn = fmaf(l, l, cn);
    }
    sInvC[wv][lane] = 20.f / (sqrtf(cn) + EPSF);
    float mz = -1e30f;
#pragma unroll
    for (int j = 0; j < NR; ++j) {
      z[j] = leakyf(s[j]) * sInvR[wv][j];
      mz = fmaxf(mz, z[j]);
    }
    float s1 = 0.f;
#pragma unroll
    for (int j = 0; j < NR; ++j) { z[j] = __expf(z[j] - mz); s1 += z[j]; }
    const float thr = s1 * (1.f / NR);
    float num = 0.f;
#pragma unroll
    for (int j = 0; j < NR; ++j) {
      z[j] = (z[j] > thr) ? z[j] : 0.f;  // focal mask; renorm cancels
      num = fmaf(z[j], s[j], num);
    }
    const float* Gp = Gimg + (size_t)i * (NR * NR);  // uniform -> s_load
    float den2 = 0.f;
#pragma unroll
    for (int j = 0; j < NR; ++j) {
      float h = 0.5f * z[j] * Gp[j * NR + j];
#pragma unroll
      for (int j2 = j + 1; j2 < NR; ++j2) h = fmaf(z[j2], Gp[j * NR + j2], h);
      den2 = fmaf(z[j], h, den2);
    }
    t2i_task = num / (capn[c * NW + lane] * sqrtf(2.f * den2) + 1e-30f);
  }
  __syncthreads();
  // ---- phase C: i2t, lane = image region r < 36 ----
  float i2t_task = 0.f;
  if (lane < NR) {
    float z[NW];
    float mz = -1e30f;
#pragma unroll
    for (int w = 0; w < NW; ++w) {
      z[w] = leakyf(srow[w]) * sInvC[wv][w];
      mz = fmaxf(mz, z[w]);
    }
    float s1 = 0.f;
#pragma unroll
    for (int w = 0; w < NW; ++w) { z[w] = __expf(z[w] - mz); s1 += z[w]; }
    const float thr = s1 * (1.f / NW);
    float num = 0.f;
#pragma unroll
    for (int w = 0; w < NW; ++w) {
      z[w] = (z[w] > thr) ? z[w] : 0.f;
      num = fmaf(z[w], srow[w], num);
    }
    const int cu = __builtin_amdgcn_readfirstlane(c);
    const float* Gp = Gcap + (size_t)cu * (NW * NW);  // uniform -> s_load
    float den2 = 0.f;
#pragma unroll
    for (int w = 0; w < NW; ++w) {
      float h = 0.5f * z[w] * Gp[w * NW + w];
#pragma unroll
      for (int w2 = w + 1; w2 < NW; ++w2) h = fmaf(z[w2], Gp[w * NW + w2], h);
      den2 = fmaf(z[w], h, den2);
    }
    i2t_task = num / (imgn[i * NR + lane] * sqrtf(2.f * den2) + 1e-30f);
  }
  // ---- reduce: mean over w of t2i + mean over r of i2t ----
  float contrib = t2i_task * (1.f / NW) + i2t_task * (1.f / NR);
#pragma unroll
  for (int d = 32; d; d >>= 1) contrib += __shfl_xor(contrib, d, 64);
  if (lane == 0) out[(size_t)i * 128 + c] = contrib;
}

extern "C" void kernel_launch(void* const* d_in, const int* in_sizes, int n_in,
                              void* d_out, int out_size, void* d_ws, size_t ws_size,
                              hipStream_t stream) {
  (void)in_sizes; (void)n_in; (void)out_size; (void)ws_size;
  const float* images = (const float*)d_in[0];
  const float* captions = (const float*)d_in[1];
  float* out = (float*)d_out;

  char* wb = (char*)d_ws;
  _Float16* Bh = (_Float16*)wb; wb += (size_t)4096 * 1024 * 2;   // frag layout
  _Float16* Bl = (_Float16*)wb; wb += (size_t)4096 * 1024 * 2;
  _Float16* Ah = (_Float16*)wb; wb += (size_t)4608 * 1024 * 2;   // linear layout
  _Float16* Al = (_Float16*)wb; wb += (size_t)4608 * 1024 * 2;
  float* Gimg = (float*)wb; wb += (size_t)128 * 1296 * 4;
  float* Gcap = (float*)wb; wb += (size_t)128 * 1024 * 4;
  float* imgn = (float*)wb; wb += (size_t)128 * 36 * 4;
  float* capn = (float*)wb; wb += (size_t)128 * 32 * 4;
  float* C = (float*)wb;                                          // 4608*4096 f32

  gram_img_kernel<<<128, 256, 0, stream>>>(images, Gimg, imgn);
  gram_cap_kernel<<<128, 256, 0, stream>>>(captions, Gcap, capn);
  split_f16_kernel<<<4608, 256, 0, stream>>>(images, Ah, Al, 4608 * 1024 / 4);
  split_b_kernel<<<2048, 256, 0, stream>>>(captions, Bh, Bl);
  mfma_gemm_kernel<<<dim3(36, 32), 128, 0, stream>>>(Ah, Al, Bh, Bl, C);
  fused_attn_kernel<<<dim3(128, 32), 256, 0, stream>>>(C, Gimg, Gcap, imgn, capn, out);
}

// Round 5
// 355.896 us; speedup vs baseline: 2.2715x; 1.1273x over previous
//
#include <hip/hip_runtime.h>
#include <math.h>

#define NR 36
#define NW 32
#define DD 1024
#define EPSF 1e-8f

typedef _Float16 f16x8 __attribute__((ext_vector_type(8)));
typedef _Float16 f16x4 __attribute__((ext_vector_type(4)));
typedef float f32x16 __attribute__((ext_vector_type(16)));
#define MFMA32(a, b, c) __builtin_amdgcn_mfma_f32_32x32x16_f16((a), (b), (c), 0, 0, 0)
#define GLD16(srcp, dstp)                                                              \
  __builtin_amdgcn_global_load_lds((const __attribute__((address_space(1))) void*)(srcp), \
                                   (__attribute__((address_space(3))) void*)(dstp), 16, 0, 0)

__device__ __forceinline__ float leakyf(float x) { return x > 0.f ? x : 0.1f * x; }

// ============ prep: grams (full symmetric) + norms + f16 hi/lo fragment planes ============
// blocks 0..127: image i ; blocks 128..255: caption cb
// Frag layout (f16): X[((mt*128 + (k>>3))*32 + ml)*8 + (k&7)], mt = row/32, ml = row%32
__global__ __launch_bounds__(256) void prep_kernel(
    const float* __restrict__ img, const float* __restrict__ cap,
    float* __restrict__ Gimg, float* __restrict__ Gcap,
    float* __restrict__ imgn, float* __restrict__ capn,
    _Float16* __restrict__ Ahf, _Float16* __restrict__ Alf,
    _Float16* __restrict__ Bhf, _Float16* __restrict__ Blf) {
  __shared__ float sA[NR][68];
  const int t = threadIdx.x;
  if (blockIdx.x < 128) {
    const int i = blockIdx.x;
    const float* A = img + (size_t)i * NR * DD;
    int ti = 0, tj = 0;
    const bool active = t < 171;  // 18*19/2 upper-tri 2x2 tiles
    if (active) {
      int rem = t, rl = 18;
      while (rem >= rl) { rem -= rl; ++ti; --rl; }
      tj = ti + rem;
    }
    const int a0 = 2 * ti, a1 = 2 * ti + 1, b0 = 2 * tj, b1 = 2 * tj + 1;
    float g00 = 0.f, g01 = 0.f, g10 = 0.f, g11 = 0.f;
    for (int k0 = 0; k0 < DD; k0 += 64) {
      for (int s = t; s < NR * 16; s += 256) {
        const int r = s >> 4, kq = s & 15;
        const float4 v = *(const float4*)(A + r * DD + k0 + kq * 4);
        *(float4*)&sA[r][kq * 4] = v;
        const int m = i * NR + r, mt = m >> 5, ml = m & 31, kk = k0 + kq * 4;
        const size_t fo = (((size_t)mt * 128 + (kk >> 3)) * 32 + ml) * 8 + (kk & 7);
        const _Float16 h0 = (_Float16)v.x, h1 = (_Float16)v.y, h2 = (_Float16)v.z,
                       h3 = (_Float16)v.w;
        f16x4 hv = {h0, h1, h2, h3};
        f16x4 lv = {(_Float16)(v.x - (float)h0), (_Float16)(v.y - (float)h1),
                    (_Float16)(v.z - (float)h2), (_Float16)(v.w - (float)h3)};
        *(f16x4*)(Ahf + fo) = hv;
        *(f16x4*)(Alf + fo) = lv;
      }
      __syncthreads();
      if (active) {
#pragma unroll
        for (int k = 0; k < 16; ++k) {
          const float4 va0 = *(const float4*)&sA[a0][k * 4];
          const float4 va1 = *(const float4*)&sA[a1][k * 4];
          const float4 vb0 = *(const float4*)&sA[b0][k * 4];
          const float4 vb1 = *(const float4*)&sA[b1][k * 4];
          g00 = fmaf(va0.x, vb0.x, g00); g00 = fmaf(va0.y, vb0.y, g00);
          g00 = fmaf(va0.z, vb0.z, g00); g00 = fmaf(va0.w, vb0.w, g00);
          g01 = fmaf(va0.x, vb1.x, g01); g01 = fmaf(va0.y, vb1.y, g01);
          g01 = fmaf(va0.z, vb1.z, g01); g01 = fmaf(va0.w, vb1.w, g01);
          g10 = fmaf(va1.x, vb0.x, g10); g10 = fmaf(va1.y, vb0.y, g10);
          g10 = fmaf(va1.z, vb0.z, g10); g10 = fmaf(va1.w, vb0.w, g10);
          g11 = fmaf(va1.x, vb1.x, g11); g11 = fmaf(va1.y, vb1.y, g11);
          g11 = fmaf(va1.z, vb1.z, g11); g11 = fmaf(va1.w, vb1.w, g11);
        }
      }
      __syncthreads();
    }
    if (active) {
      float* Gi = Gimg + (size_t)i * NR * NR;
      Gi[a0 * NR + b0] = g00; Gi[b0 * NR + a0] = g00;
      Gi[a0 * NR + b1] = g01; Gi[b1 * NR + a0] = g01;
      Gi[a1 * NR + b0] = g10; Gi[b0 * NR + a1] = g10;
      Gi[a1 * NR + b1] = g11; Gi[b1 * NR + a1] = g11;
      if (ti == tj) {
        imgn[i * NR + a0] = fmaxf(sqrtf(g00), EPSF);
        imgn[i * NR + a1] = fmaxf(sqrtf(g11), EPSF);
      }
    }
  } else {
    const int cb = blockIdx.x - 128;
    const float* A = cap + (size_t)cb * NW * DD;
    int ti = 0, tj = 0;
    const bool active = t < 136;  // 16*17/2
    if (active) {
      int rem = t, rl = 16;
      while (rem >= rl) { rem -= rl; ++ti; --rl; }
      tj = ti + rem;
    }
    const int a0 = 2 * ti, a1 = 2 * ti + 1, b0 = 2 * tj, b1 = 2 * tj + 1;
    float g00 = 0.f, g01 = 0.f, g10 = 0.f, g11 = 0.f;
    for (int k0 = 0; k0 < DD; k0 += 64) {
      for (int s = t; s < NW * 16; s += 256) {
        const int w = s >> 4, kq = s & 15;
        const float4 v = *(const float4*)(A + w * DD + k0 + kq * 4);
        *(float4*)&sA[w][kq * 4] = v;
        const int kk = k0 + kq * 4;
        const size_t fo = (((size_t)cb * 128 + (kk >> 3)) * 32 + w) * 8 + (kk & 7);
        const _Float16 h0 = (_Float16)v.x, h1 = (_Float16)v.y, h2 = (_Float16)v.z,
                       h3 = (_Float16)v.w;
        f16x4 hv = {h0, h1, h2, h3};
        f16x4 lv = {(_Float16)(v.x - (float)h0), (_Float16)(v.y - (float)h1),
                    (_Float16)(v.z - (float)h2), (_Float16)(v.w - (float)h3)};
        *(f16x4*)(Bhf + fo) = hv;
        *(f16x4*)(Blf + fo) = lv;
      }
      __syncthreads();
      if (active) {
#pragma unroll
        for (int k = 0; k < 16; ++k) {
          const float4 va0 = *(const float4*)&sA[a0][k * 4];
          const float4 va1 = *(const float4*)&sA[a1][k * 4];
          const float4 vb0 = *(const float4*)&sA[b0][k * 4];
          const float4 vb1 = *(const float4*)&sA[b1][k * 4];
          g00 = fmaf(va0.x, vb0.x, g00); g00 = fmaf(va0.y, vb0.y, g00);
          g00 = fmaf(va0.z, vb0.z, g00); g00 = fmaf(va0.w, vb0.w, g00);
          g01 = fmaf(va0.x, vb1.x, g01); g01 = fmaf(va0.y, vb1.y, g01);
          g01 = fmaf(va0.z, vb1.z, g01); g01 = fmaf(va0.w, vb1.w, g01);
          g10 = fmaf(va1.x, vb0.x, g10); g10 = fmaf(va1.y, vb0.y, g10);
          g10 = fmaf(va1.z, vb0.z, g10); g10 = fmaf(va1.w, vb0.w, g10);
          g11 = fmaf(va1.x, vb1.x, g11); g11 = fmaf(va1.y, vb1.y, g11);
          g11 = fmaf(va1.z, vb1.z, g11); g11 = fmaf(va1.w, vb1.w, g11);
        }
      }
      __syncthreads();
    }
    if (active) {
      float* Gc = Gcap + (size_t)cb * NW * NW;
      Gc[a0 * NW + b0] = g00; Gc[b0 * NW + a0] = g00;
      Gc[a0 * NW + b1] = g01; Gc[b1 * NW + a0] = g01;
      Gc[a1 * NW + b0] = g10; Gc[b0 * NW + a1] = g10;
      Gc[a1 * NW + b1] = g11; Gc[b1 * NW + a1] = g11;
      if (ti == tj) {
        capn[cb * NW + a0] = fmaxf(sqrtf(g00), EPSF);
        capn[cb * NW + a1] = fmaxf(sqrtf(g11), EPSF);
      }
    }
  }
}

// ============ MFMA GEMM: B double-buffered in LDS (DMA), A direct global (frag layout) ====
__device__ __forceinline__ void gemm_loadA(const _Float16* __restrict__ Ahf,
                                           const _Float16* __restrict__ Alf, int Mt0, int kt,
                                           int kb, int lm, f16x8 ar[2][2][2]) {
#pragma unroll
  for (int mt = 0; mt < 2; ++mt)
#pragma unroll
    for (int ks = 0; ks < 2; ++ks) {
      const size_t o = (((size_t)(Mt0 + mt) * 128) + kt * 4 + ks * 2 + kb) * 256 + lm * 8;
      ar[mt][ks][0] = *(const f16x8*)(Ahf + o);
      ar[mt][ks][1] = *(const f16x8*)(Alf + o);
    }
}

__device__ __forceinline__ void gemm_compute(const _Float16* __restrict__ sb,
                                             const f16x8 ar[2][2][2], f32x16 acc[2][4], int kb,
                                             int lm) {
#pragma unroll
  for (int ks = 0; ks < 2; ++ks) {
#pragma unroll
    for (int nt = 0; nt < 4; ++nt) {
      const int co = (nt * 4 + ks * 2 + kb) * 512 + lm * 8;
      const f16x8 bh = *(const f16x8*)&sb[co];
      const f16x8 bl = *(const f16x8*)&sb[co + 256];
      acc[0][nt] = MFMA32(ar[0][ks][0], bh, acc[0][nt]);
      acc[1][nt] = MFMA32(ar[1][ks][0], bh, acc[1][nt]);
      acc[0][nt] = MFMA32(ar[0][ks][1], bh, acc[0][nt]);
      acc[1][nt] = MFMA32(ar[1][ks][1], bh, acc[1][nt]);
      acc[0][nt] = MFMA32(ar[0][ks][0], bl, acc[0][nt]);
      acc[1][nt] = MFMA32(ar[1][ks][0], bl, acc[1][nt]);
    }
  }
}

// grid 1152 (1D): yb = bid&31 (n-slice -> XCD residue), xb = bid>>5. Block 128 thr, tile 128x128.
__global__ __launch_bounds__(128) void mfma_gemm_kernel(
    const _Float16* __restrict__ Ahf, const _Float16* __restrict__ Alf,
    const _Float16* __restrict__ Bhf, const _Float16* __restrict__ Blf, float* __restrict__ C) {
  __shared__ _Float16 sB[2][8192];  // 2 x 16 KB
  const int bid = blockIdx.x;
  const int yb = bid & 31, xb = bid >> 5;
  const int n0b = yb * 4;
  const int tid = threadIdx.x;
  const int wv = tid >> 6, lane = tid & 63;
  const int lm = lane & 31, kb = lane >> 5;
  const int Mt0 = xb * 4 + wv * 2;
  const _Float16* Bsrc = kb ? Blf : Bhf;

  auto stageB = [&](int kt, int buf) {
#pragma unroll
    for (int u = 0; u < 8; ++u) {
      const int cp = wv * 8 + u;  // 0..15 = nb*4 + kq
      const int nb = cp >> 2, kq = cp & 3;
      const _Float16* src = Bsrc + (((size_t)(n0b + nb) * 128 + kt * 4 + kq) * 32 + lm) * 8;
      GLD16(src, &sB[buf][cp * 512]);
    }
  };

  f32x16 acc[2][4];
#pragma unroll
  for (int a = 0; a < 2; ++a)
#pragma unroll
    for (int b = 0; b < 4; ++b) acc[a][b] = {};
  f16x8 ar0[2][2][2], ar1[2][2][2];

  stageB(0, 0);
  gemm_loadA(Ahf, Alf, Mt0, 0, kb, lm, ar0);
  for (int kt2 = 0; kt2 < 16; ++kt2) {
    const int kt = kt2 * 2;
    __syncthreads();  // drains DMA(kt) + A(kt); protects buffers
    if (kt + 1 < 32) {
      stageB(kt + 1, 1);
      gemm_loadA(Ahf, Alf, Mt0, kt + 1, kb, lm, ar1);
    }
    gemm_compute(sB[0], ar0, acc, kb, lm);
    __syncthreads();  // drains DMA(kt+1) + A(kt+1) (covered by compute above)
    if (kt + 2 < 32) {
      stageB(kt + 2, 0);
      gemm_loadA(Ahf, Alf, Mt0, kt + 2, kb, lm, ar0);
    }
    gemm_compute(sB[1], ar1, acc, kb, lm);
  }
  // epilogue: C/D layout col=lane&31, row=(q&3)+8*(q>>2)+4*kb ; C[((il*128+c)*36+r)*32+w]
#pragma unroll
  for (int mt = 0; mt < 2; ++mt)
#pragma unroll
    for (int nt = 0; nt < 4; ++nt) {
      const int cc = n0b + nt;
      const f32x16 a = acc[mt][nt];
#pragma unroll
      for (int q = 0; q < 16; ++q) {
        const int row32 = (q & 3) + 8 * (q >> 2) + 4 * kb;
        const int m = (Mt0 + mt) * 32 + row32;
        const int il = m / NR, r = m - il * NR;
        C[((size_t)il * 128 + cc) * (NR * NW) + r * NW + lm] = a[q];
      }
    }
}

// ============ fused post-GEMM: G staged in LDS, full-symmetric quadratic forms ============
__global__ __launch_bounds__(256) void fused_attn_kernel(
    const float* __restrict__ C, const float* __restrict__ Gimg, const float* __restrict__ Gcap,
    const float* __restrict__ imgn, const float* __restrict__ capn, float* __restrict__ out) {
  const int i = blockIdx.x;
  const int cg = blockIdx.y;
  const int tid = threadIdx.x;
  const int wv = tid >> 6, lane = tid & 63;
  const int c = cg * 4 + wv;
  __shared__ float sGi[NR * NR];
  __shared__ float sGc[4][NW * NW];
  __shared__ float sS[4][NR * NR];
  __shared__ float sInvR[4][NR];
  __shared__ float sInvC[4][NW];
  for (int t = tid; t < NR * NR; t += 256) sGi[t] = Gimg[(size_t)i * (NR * NR) + t];
  for (int t = tid; t < 4 * NW * NW; t += 256)
    sGc[t >> 10][t & 1023] = Gcap[(size_t)(cg * 4 + (t >> 10)) * (NW * NW) + (t & 1023)];
  const float* Cp = C + ((size_t)i * 128 + c) * (NR * NW);
  float srow[NW];
  // ---- phase A: lane r<36 loads its S row, row norm over w ----
  if (lane < NR) {
    const float* rp = Cp + lane * NW;
#pragma unroll
    for (int j = 0; j < 8; ++j) {
      const float4 v = *(const float4*)(rp + 4 * j);
      srow[4 * j + 0] = v.x; srow[4 * j + 1] = v.y;
      srow[4 * j + 2] = v.z; srow[4 * j + 3] = v.w;
      *(float4*)&sS[wv][lane * NR + 4 * j] = v;
    }
    float rn = 0.f;
#pragma unroll
    for (int w = 0; w < NW; ++w) { const float l = leakyf(srow[w]); rn = fmaf(l, l, rn); }
    sInvR[wv][lane] = 20.f / (sqrtf(rn) + EPSF);
  }
  __syncthreads();
  // ---- phase B: t2i, lane = caption word w < 32 ----
  float t2i_task = 0.f;
  if (lane < NW) {
    float s[NR], z[NR];
    float cn = 0.f;
#pragma unroll
    for (int j = 0; j < NR; ++j) {
      s[j] = sS[wv][j * NR + lane];
      const float l = leakyf(s[j]);
      cn = fmaf(l, l, cn);
    }
    sInvC[wv][lane] = 20.f / (sqrtf(cn) + EPSF);
    float mz = -1e30f;
#pragma unroll
    for (int j = 0; j < NR; ++j) {
      z[j] = leakyf(s[j]) * sInvR[wv][j];
      mz = fmaxf(mz, z[j]);
    }
    float s1 = 0.f;
#pragma unroll
    for (int j = 0; j < NR; ++j) { z[j] = __expf(z[j] - mz); s1 += z[j]; }
    const float thr = s1 * (1.f / NR);
    float num = 0.f;
#pragma unroll
    for (int j = 0; j < NR; ++j) {
      z[j] = (z[j] > thr) ? z[j] : 0.f;  // focal mask; renorm cancels
      num = fmaf(z[j], s[j], num);
    }
    float den2 = 0.f;
#pragma unroll
    for (int j = 0; j < NR; ++j) {
      float h = 0.f;
#pragma unroll
      for (int j2 = 0; j2 < NR; j2 += 4) {
        const float4 gv = *(const float4*)&sGi[j * NR + j2];
        h = fmaf(z[j2 + 0], gv.x, h); h = fmaf(z[j2 + 1], gv.y, h);
        h = fmaf(z[j2 + 2], gv.z, h); h = fmaf(z[j2 + 3], gv.w, h);
      }
      den2 = fmaf(z[j], h, den2);
    }
    t2i_task = num / (capn[c * NW + lane] * sqrtf(den2) + 1e-30f);
  }
  __syncthreads();
  // ---- phase C: i2t, lane = image region r < 36 ----
  float i2t_task = 0.f;
  if (lane < NR) {
    float z[NW];
    float mz = -1e30f;
#pragma unroll
    for (int w = 0; w < NW; ++w) {
      z[w] = leakyf(srow[w]) * sInvC[wv][w];
      mz = fmaxf(mz, z[w]);
    }
    float s1 = 0.f;
#pragma unroll
    for (int w = 0; w < NW; ++w) { z[w] = __expf(z[w] - mz); s1 += z[w]; }
    const float thr = s1 * (1.f / NW);
    float num = 0.f;
#pragma unroll
    for (int w = 0; w < NW; ++w) {
      z[w] = (z[w] > thr) ? z[w] : 0.f;
      num = fmaf(z[w], srow[w], num);
    }
    float den2 = 0.f;
#pragma unroll
    for (int w = 0; w < NW; ++w) {
      float h = 0.f;
#pragma unroll
      for (int w2 = 0; w2 < NW; w2 += 4) {
        const float4 gv = *(const float4*)&sGc[wv][w * NW + w2];
        h = fmaf(z[w2 + 0], gv.x, h); h = fmaf(z[w2 + 1], gv.y, h);
        h = fmaf(z[w2 + 2], gv.z, h); h = fmaf(z[w2 + 3], gv.w, h);
      }
      den2 = fmaf(z[w], h, den2);
    }
    i2t_task = num / (imgn[i * NR + lane] * sqrtf(den2) + 1e-30f);
  }
  float contrib = t2i_task * (1.f / NW) + i2t_task * (1.f / NR);
#pragma unroll
  for (int d = 32; d; d >>= 1) contrib += __shfl_xor(contrib, d, 64);
  if (lane == 0) out[(size_t)i * 128 + c] = contrib;
}

extern "C" void kernel_launch(void* const* d_in, const int* in_sizes, int n_in,
                              void* d_out, int out_size, void* d_ws, size_t ws_size,
                              hipStream_t stream) {
  (void)in_sizes; (void)n_in; (void)out_size; (void)ws_size;
  const float* images = (const float*)d_in[0];
  const float* captions = (const float*)d_in[1];
  float* out = (float*)d_out;

  char* wb = (char*)d_ws;
  _Float16* Ahf = (_Float16*)wb; wb += (size_t)4608 * 1024 * 2;  // frag layout
  _Float16* Alf = (_Float16*)wb; wb += (size_t)4608 * 1024 * 2;
  _Float16* Bhf = (_Float16*)wb; wb += (size_t)4096 * 1024 * 2;
  _Float16* Blf = (_Float16*)wb; wb += (size_t)4096 * 1024 * 2;
  float* Gimg = (float*)wb; wb += (size_t)128 * NR * NR * 4;     // full symmetric
  float* Gcap = (float*)wb; wb += (size_t)128 * NW * NW * 4;
  float* imgn = (float*)wb; wb += (size_t)128 * NR * 4;
  float* capn = (float*)wb; wb += (size_t)128 * NW * 4;
  float* C = (float*)wb;                                          // 4608*4096 f32 = 75.5 MB

  prep_kernel<<<256, 256, 0, stream>>>(images, captions, Gimg, Gcap, imgn, capn,
                                       Ahf, Alf, Bhf, Blf);
  mfma_gemm_kernel<<<1152, 128, 0, stream>>>(Ahf, Alf, Bhf, Blf, C);
  fused_attn_kernel<<<dim3(128, 32), 256, 0, stream>>>(C, Gimg, Gcap, imgn, capn, out);
}

// Round 6
// 333.461 us; speedup vs baseline: 2.4243x; 1.0673x over previous
//
#include <hip/hip_runtime.h>
#include <math.h>

#define NR 36
#define NW 32
#define DD 1024
#define EPSF 1e-8f

typedef _Float16 f16x8 __attribute__((ext_vector_type(8)));
typedef _Float16 f16x4 __attribute__((ext_vector_type(4)));
typedef float f32x16 __attribute__((ext_vector_type(16)));
#define MFMA32(a, b, c) __builtin_amdgcn_mfma_f32_32x32x16_f16((a), (b), (c), 0, 0, 0)
#define GLD16(srcp, dstp)                                                              \
  __builtin_amdgcn_global_load_lds((const __attribute__((address_space(1))) void*)(srcp), \
                                   (__attribute__((address_space(3))) void*)(dstp), 16, 0, 0)

__device__ __forceinline__ float leakyf(float x) { return x > 0.f ? x : 0.1f * x; }

// ============ prep: grams (full symmetric) + norms + f16 hi/lo fragment planes ============
// blocks 0..127: image i ; blocks 128..255: caption cb
// Frag layout (f16): X[((mt*128 + (k>>3))*32 + ml)*8 + (k&7)], mt = row/32, ml = row%32
// Split store loop: lanes sweep ROWS, each thread emits a full f16x8 -> coalesced 16B stores.
__global__ __launch_bounds__(256) void prep_kernel(
    const float* __restrict__ img, const float* __restrict__ cap,
    float* __restrict__ Gimg, float* __restrict__ Gcap,
    float* __restrict__ imgn, float* __restrict__ capn,
    _Float16* __restrict__ Ahf, _Float16* __restrict__ Alf,
    _Float16* __restrict__ Bhf, _Float16* __restrict__ Blf) {
  __shared__ float sA[NR][68];
  const int t = threadIdx.x;
  if (blockIdx.x < 128) {
    const int i = blockIdx.x;
    const float* A = img + (size_t)i * NR * DD;
    int ti = 0, tj = 0;
    const bool active = t < 171;  // 18*19/2 upper-tri 2x2 tiles
    if (active) {
      int rem = t, rl = 18;
      while (rem >= rl) { rem -= rl; ++ti; --rl; }
      tj = ti + rem;
    }
    const int a0 = 2 * ti, a1 = 2 * ti + 1, b0 = 2 * tj, b1 = 2 * tj + 1;
    float g00 = 0.f, g01 = 0.f, g10 = 0.f, g11 = 0.f;
    for (int k0 = 0; k0 < DD; k0 += 64) {
      for (int s = t; s < NR * 8; s += 256) {  // 288 tasks: kq8 = s/36, r = s%36
        const int kq8 = s / NR, r = s - kq8 * NR;
        const int kk = k0 + kq8 * 8;
        const float4 v0 = *(const float4*)(A + r * DD + kk);
        const float4 v1 = *(const float4*)(A + r * DD + kk + 4);
        *(float4*)&sA[r][kq8 * 8] = v0;
        *(float4*)&sA[r][kq8 * 8 + 4] = v1;
        const float a[8] = {v0.x, v0.y, v0.z, v0.w, v1.x, v1.y, v1.z, v1.w};
        f16x8 hv, lv;
#pragma unroll
        for (int j = 0; j < 8; ++j) {
          const _Float16 hh = (_Float16)a[j];
          hv[j] = hh;
          lv[j] = (_Float16)(a[j] - (float)hh);
        }
        const int m = i * NR + r, mt = m >> 5, ml = m & 31;
        const size_t fo = (((size_t)mt * 128 + (kk >> 3)) * 32 + ml) * 8;
        *(f16x8*)(Ahf + fo) = hv;
        *(f16x8*)(Alf + fo) = lv;
      }
      __syncthreads();
      if (active) {
#pragma unroll
        for (int k = 0; k < 16; ++k) {
          const float4 va0 = *(const float4*)&sA[a0][k * 4];
          const float4 va1 = *(const float4*)&sA[a1][k * 4];
          const float4 vb0 = *(const float4*)&sA[b0][k * 4];
          const float4 vb1 = *(const float4*)&sA[b1][k * 4];
          g00 = fmaf(va0.x, vb0.x, g00); g00 = fmaf(va0.y, vb0.y, g00);
          g00 = fmaf(va0.z, vb0.z, g00); g00 = fmaf(va0.w, vb0.w, g00);
          g01 = fmaf(va0.x, vb1.x, g01); g01 = fmaf(va0.y, vb1.y, g01);
          g01 = fmaf(va0.z, vb1.z, g01); g01 = fmaf(va0.w, vb1.w, g01);
          g10 = fmaf(va1.x, vb0.x, g10); g10 = fmaf(va1.y, vb0.y, g10);
          g10 = fmaf(va1.z, vb0.z, g10); g10 = fmaf(va1.w, vb0.w, g10);
          g11 = fmaf(va1.x, vb1.x, g11); g11 = fmaf(va1.y, vb1.y, g11);
          g11 = fmaf(va1.z, vb1.z, g11); g11 = fmaf(va1.w, vb1.w, g11);
        }
      }
      __syncthreads();
    }
    if (active) {
      float* Gi = Gimg + (size_t)i * NR * NR;
      Gi[a0 * NR + b0] = g00; Gi[b0 * NR + a0] = g00;
      Gi[a0 * NR + b1] = g01; Gi[b1 * NR + a0] = g01;
      Gi[a1 * NR + b0] = g10; Gi[b0 * NR + a1] = g10;
      Gi[a1 * NR + b1] = g11; Gi[b1 * NR + a1] = g11;
      if (ti == tj) {
        imgn[i * NR + a0] = fmaxf(sqrtf(g00), EPSF);
        imgn[i * NR + a1] = fmaxf(sqrtf(g11), EPSF);
      }
    }
  } else {
    const int cb = blockIdx.x - 128;
    const float* A = cap + (size_t)cb * NW * DD;
    int ti = 0, tj = 0;
    const bool active = t < 136;  // 16*17/2
    if (active) {
      int rem = t, rl = 16;
      while (rem >= rl) { rem -= rl; ++ti; --rl; }
      tj = ti + rem;
    }
    const int a0 = 2 * ti, a1 = 2 * ti + 1, b0 = 2 * tj, b1 = 2 * tj + 1;
    float g00 = 0.f, g01 = 0.f, g10 = 0.f, g11 = 0.f;
    for (int k0 = 0; k0 < DD; k0 += 64) {
      {  // 256 tasks: kq8 = s>>5, r = s&31
        const int s = t;
        const int kq8 = s >> 5, r = s & 31;
        const int kk = k0 + kq8 * 8;
        const float4 v0 = *(const float4*)(A + r * DD + kk);
        const float4 v1 = *(const float4*)(A + r * DD + kk + 4);
        *(float4*)&sA[r][kq8 * 8] = v0;
        *(float4*)&sA[r][kq8 * 8 + 4] = v1;
        const float a[8] = {v0.x, v0.y, v0.z, v0.w, v1.x, v1.y, v1.z, v1.w};
        f16x8 hv, lv;
#pragma unroll
        for (int j = 0; j < 8; ++j) {
          const _Float16 hh = (_Float16)a[j];
          hv[j] = hh;
          lv[j] = (_Float16)(a[j] - (float)hh);
        }
        const size_t fo = (((size_t)cb * 128 + (kk >> 3)) * 32 + r) * 8;
        *(f16x8*)(Bhf + fo) = hv;
        *(f16x8*)(Blf + fo) = lv;
      }
      __syncthreads();
      if (active) {
#pragma unroll
        for (int k = 0; k < 16; ++k) {
          const float4 va0 = *(const float4*)&sA[a0][k * 4];
          const float4 va1 = *(const float4*)&sA[a1][k * 4];
          const float4 vb0 = *(const float4*)&sA[b0][k * 4];
          const float4 vb1 = *(const float4*)&sA[b1][k * 4];
          g00 = fmaf(va0.x, vb0.x, g00); g00 = fmaf(va0.y, vb0.y, g00);
          g00 = fmaf(va0.z, vb0.z, g00); g00 = fmaf(va0.w, vb0.w, g00);
          g01 = fmaf(va0.x, vb1.x, g01); g01 = fmaf(va0.y, vb1.y, g01);
          g01 = fmaf(va0.z, vb1.z, g01); g01 = fmaf(va0.w, vb1.w, g01);
          g10 = fmaf(va1.x, vb0.x, g10); g10 = fmaf(va1.y, vb0.y, g10);
          g10 = fmaf(va1.z, vb0.z, g10); g10 = fmaf(va1.w, vb0.w, g10);
          g11 = fmaf(va1.x, vb1.x, g11); g11 = fmaf(va1.y, vb1.y, g11);
          g11 = fmaf(va1.z, vb1.z, g11); g11 = fmaf(va1.w, vb1.w, g11);
        }
      }
      __syncthreads();
    }
    if (active) {
      float* Gc = Gcap + (size_t)cb * NW * NW;
      Gc[a0 * NW + b0] = g00; Gc[b0 * NW + a0] = g00;
      Gc[a0 * NW + b1] = g01; Gc[b1 * NW + a0] = g01;
      Gc[a1 * NW + b0] = g10; Gc[b0 * NW + a1] = g10;
      Gc[a1 * NW + b1] = g11; Gc[b1 * NW + a1] = g11;
      if (ti == tj) {
        capn[cb * NW + a0] = fmaxf(sqrtf(g00), EPSF);
        capn[cb * NW + a1] = fmaxf(sqrtf(g11), EPSF);
      }
    }
  }
}

// ============ MFMA GEMM: B double-buffered in LDS (DMA), A direct global (frag layout) ====
// (unchanged from round 5 — at the m97-structure plateau, 847 TF)
__device__ __forceinline__ void gemm_loadA(const _Float16* __restrict__ Ahf,
                                           const _Float16* __restrict__ Alf, int Mt0, int kt,
                                           int kb, int lm, f16x8 ar[2][2][2]) {
#pragma unroll
  for (int mt = 0; mt < 2; ++mt)
#pragma unroll
    for (int ks = 0; ks < 2; ++ks) {
      const size_t o = (((size_t)(Mt0 + mt) * 128) + kt * 4 + ks * 2 + kb) * 256 + lm * 8;
      ar[mt][ks][0] = *(const f16x8*)(Ahf + o);
      ar[mt][ks][1] = *(const f16x8*)(Alf + o);
    }
}

__device__ __forceinline__ void gemm_compute(const _Float16* __restrict__ sb,
                                             const f16x8 ar[2][2][2], f32x16 acc[2][4], int kb,
                                             int lm) {
#pragma unroll
  for (int ks = 0; ks < 2; ++ks) {
#pragma unroll
    for (int nt = 0; nt < 4; ++nt) {
      const int co = (nt * 4 + ks * 2 + kb) * 512 + lm * 8;
      const f16x8 bh = *(const f16x8*)&sb[co];
      const f16x8 bl = *(const f16x8*)&sb[co + 256];
      acc[0][nt] = MFMA32(ar[0][ks][0], bh, acc[0][nt]);
      acc[1][nt] = MFMA32(ar[1][ks][0], bh, acc[1][nt]);
      acc[0][nt] = MFMA32(ar[0][ks][1], bh, acc[0][nt]);
      acc[1][nt] = MFMA32(ar[1][ks][1], bh, acc[1][nt]);
      acc[0][nt] = MFMA32(ar[0][ks][0], bl, acc[0][nt]);
      acc[1][nt] = MFMA32(ar[1][ks][0], bl, acc[1][nt]);
    }
  }
}

__global__ __launch_bounds__(128) void mfma_gemm_kernel(
    const _Float16* __restrict__ Ahf, const _Float16* __restrict__ Alf,
    const _Float16* __restrict__ Bhf, const _Float16* __restrict__ Blf, float* __restrict__ C) {
  __shared__ _Float16 sB[2][8192];
  const int bid = blockIdx.x;
  const int yb = bid & 31, xb = bid >> 5;
  const int n0b = yb * 4;
  const int tid = threadIdx.x;
  const int wv = tid >> 6, lane = tid & 63;
  const int lm = lane & 31, kb = lane >> 5;
  const int Mt0 = xb * 4 + wv * 2;
  const _Float16* Bsrc = kb ? Blf : Bhf;

  auto stageB = [&](int kt, int buf) {
#pragma unroll
    for (int u = 0; u < 8; ++u) {
      const int cp = wv * 8 + u;
      const int nb = cp >> 2, kq = cp & 3;
      const _Float16* src = Bsrc + (((size_t)(n0b + nb) * 128 + kt * 4 + kq) * 32 + lm) * 8;
      GLD16(src, &sB[buf][cp * 512]);
    }
  };

  f32x16 acc[2][4];
#pragma unroll
  for (int a = 0; a < 2; ++a)
#pragma unroll
    for (int b = 0; b < 4; ++b) acc[a][b] = {};
  f16x8 ar0[2][2][2], ar1[2][2][2];

  stageB(0, 0);
  gemm_loadA(Ahf, Alf, Mt0, 0, kb, lm, ar0);
  for (int kt2 = 0; kt2 < 16; ++kt2) {
    const int kt = kt2 * 2;
    __syncthreads();
    if (kt + 1 < 32) {
      stageB(kt + 1, 1);
      gemm_loadA(Ahf, Alf, Mt0, kt + 1, kb, lm, ar1);
    }
    gemm_compute(sB[0], ar0, acc, kb, lm);
    __syncthreads();
    if (kt + 2 < 32) {
      stageB(kt + 2, 0);
      gemm_loadA(Ahf, Alf, Mt0, kt + 2, kb, lm, ar0);
    }
    gemm_compute(sB[1], ar1, acc, kb, lm);
  }
#pragma unroll
  for (int mt = 0; mt < 2; ++mt)
#pragma unroll
    for (int nt = 0; nt < 4; ++nt) {
      const int cc = n0b + nt;
      const f32x16 a = acc[mt][nt];
#pragma unroll
      for (int q = 0; q < 16; ++q) {
        const int row32 = (q & 3) + 8 * (q >> 2) + 4 * kb;
        const int m = (Mt0 + mt) * 32 + row32;
        const int il = m / NR, r = m - il * NR;
        C[((size_t)il * 128 + cc) * (NR * NW) + r * NW + lm] = a[q];
      }
    }
}

// ============ fused post-GEMM: S in LDS (stride 36), G via wave-uniform s_load ============
// block = 256 thr, grid (i=128, cg=16); block handles 8 captions.
__global__ __launch_bounds__(256) void fused_attn_kernel(
    const float* __restrict__ C, const float* __restrict__ Gimg, const float* __restrict__ Gcap,
    const float* __restrict__ imgn, const float* __restrict__ capn, float* __restrict__ out) {
  const int i = blockIdx.x;
  const int cg = blockIdx.y;
  const int tid = threadIdx.x;
  const int wv = tid >> 6, lane = tid & 63;
  __shared__ float sS[8][NR * 36];   // [cap][r*36 + w]
  __shared__ float sInvR[8][NR];
  __shared__ float sInvC[8][NW];
  __shared__ float red[8];
  if (tid < 8) red[tid] = 0.f;
  // ---- stage S for 8 captions (coalesced float4) ----
  const float* Cp = C + ((size_t)i * 128 + cg * 8) * (NR * NW);
  for (int t = tid; t < 8 * NR * NW / 4; t += 256) {
    const int cap = t / (NR * NW / 4);
    const int rem = t - cap * (NR * NW / 4);
    const int r = rem >> 3, wq = rem & 7;
    const float4 v = *(const float4*)(Cp + cap * (NR * NW) + r * NW + wq * 4);
    *(float4*)&sS[cap][r * 36 + wq * 4] = v;
  }
  __syncthreads();
  // ---- row norms: 2 iters, wave-uniform cap, lane = r ----
#pragma unroll
  for (int it = 0; it < 2; ++it) {
    const int capu = wv + it * 4;
    if (lane < NR) {
      float rn = 0.f;
#pragma unroll
      for (int k = 0; k < 8; ++k) {
        const float4 v = *(const float4*)&sS[capu][lane * 36 + k * 4];
        float l;
        l = leakyf(v.x); rn = fmaf(l, l, rn);
        l = leakyf(v.y); rn = fmaf(l, l, rn);
        l = leakyf(v.z); rn = fmaf(l, l, rn);
        l = leakyf(v.w); rn = fmaf(l, l, rn);
      }
      sInvR[capu][lane] = 20.f / (sqrtf(rn) + EPSF);
    }
  }
  __syncthreads();
  // ---- t2i: 256 tasks = 8 caps x 32 words; G = Gimg[i] block-uniform -> s_load ----
  {
    const int capT = tid >> 5, wT = tid & 31;
    float s[NR], z[NR];
    float cn = 0.f;
#pragma unroll
    for (int j = 0; j < NR; ++j) {
      s[j] = sS[capT][j * 36 + wT];
      const float l = leakyf(s[j]);
      cn = fmaf(l, l, cn);
    }
    sInvC[capT][wT] = 20.f / (sqrtf(cn) + EPSF);
    float mz = -1e30f;
#pragma unroll
    for (int j = 0; j < NR; ++j) {
      z[j] = leakyf(s[j]) * sInvR[capT][j];
      mz = fmaxf(mz, z[j]);
    }
    float s1 = 0.f;
#pragma unroll
    for (int j = 0; j < NR; ++j) { z[j] = __expf(z[j] - mz); s1 += z[j]; }
    const float thr = s1 * (1.f / NR);
    float num = 0.f;
#pragma unroll
    for (int j = 0; j < NR; ++j) {
      z[j] = (z[j] > thr) ? z[j] : 0.f;  // focal mask; renorm cancels
      num = fmaf(z[j], s[j], num);
    }
    const float* Gp = Gimg + (size_t)i * (NR * NR);  // uniform -> s_load
    float den2 = 0.f;
#pragma unroll
    for (int j = 0; j < NR; ++j) {
      float h = 0.5f * z[j] * Gp[j * NR + j];
#pragma unroll
      for (int j2 = j + 1; j2 < NR; ++j2) h = fmaf(z[j2], Gp[j * NR + j2], h);
      den2 = fmaf(z[j], h, den2);
    }
    const float val = num / (capn[(cg * 8 + capT) * NW + wT] * sqrtf(2.f * den2) + 1e-30f);
    float contrib = val * (1.f / NW);
#pragma unroll
    for (int d = 1; d < 32; d <<= 1) contrib += __shfl_xor(contrib, d, 64);
    if ((tid & 31) == 0) atomicAdd(&red[capT], contrib);
  }
  __syncthreads();
  // ---- i2t: 2 iters, wave-uniform cap (-> Gcap s_load), lane = r ----
#pragma unroll
  for (int it = 0; it < 2; ++it) {
    const int capu = wv + it * 4;
    const int cglob = cg * 8 + capu;
    float contrib = 0.f;
    if (lane < NR) {
      float sr[NW], z[NW];
#pragma unroll
      for (int k = 0; k < 8; ++k)
        *(float4*)&sr[k * 4] = *(const float4*)&sS[capu][lane * 36 + k * 4];
      float mz = -1e30f;
#pragma unroll
      for (int w = 0; w < NW; ++w) {
        z[w] = leakyf(sr[w]) * sInvC[capu][w];
        mz = fmaxf(mz, z[w]);
      }
      float s1 = 0.f;
#pragma unroll
      for (int w = 0; w < NW; ++w) { z[w] = __expf(z[w] - mz); s1 += z[w]; }
      const float thr = s1 * (1.f / NW);
      float num = 0.f;
#pragma unroll
      for (int w = 0; w < NW; ++w) {
        z[w] = (z[w] > thr) ? z[w] : 0.f;
        num = fmaf(z[w], sr[w], num);
      }
      const float* Gp = Gcap + (size_t)cglob * (NW * NW);  // wave-uniform -> s_load
      float den2 = 0.f;
#pragma unroll
      for (int w = 0; w < NW; ++w) {
        float h = 0.5f * z[w] * Gp[w * NW + w];
#pragma unroll
        for (int w2 = w + 1; w2 < NW; ++w2) h = fmaf(z[w2], Gp[w * NW + w2], h);
        den2 = fmaf(z[w], h, den2);
      }
      const float val = num / (imgn[i * NR + lane] * sqrtf(2.f * den2) + 1e-30f);
      contrib = val * (1.f / NR);
    }
#pragma unroll
    for (int d = 1; d < 64; d <<= 1) contrib += __shfl_xor(contrib, d, 64);
    if (lane == 0) atomicAdd(&red[capu], contrib);
  }
  __syncthreads();
  if (tid < 8) out[(size_t)i * 128 + cg * 8 + tid] = red[tid];
}

extern "C" void kernel_launch(void* const* d_in, const int* in_sizes, int n_in,
                              void* d_out, int out_size, void* d_ws, size_t ws_size,
                              hipStream_t stream) {
  (void)in_sizes; (void)n_in; (void)out_size; (void)ws_size;
  const float* images = (const float*)d_in[0];
  const float* captions = (const float*)d_in[1];
  float* out = (float*)d_out;

  char* wb = (char*)d_ws;
  _Float16* Ahf = (_Float16*)wb; wb += (size_t)4608 * 1024 * 2;
  _Float16* Alf = (_Float16*)wb; wb += (size_t)4608 * 1024 * 2;
  _Float16* Bhf = (_Float16*)wb; wb += (size_t)4096 * 1024 * 2;
  _Float16* Blf = (_Float16*)wb; wb += (size_t)4096 * 1024 * 2;
  float* Gimg = (float*)wb; wb += (size_t)128 * NR * NR * 4;
  float* Gcap = (float*)wb; wb += (size_t)128 * NW * NW * 4;
  float* imgn = (float*)wb; wb += (size_t)128 * NR * 4;
  float* capn = (float*)wb; wb += (size_t)128 * NW * 4;
  float* C = (float*)wb;

  prep_kernel<<<256, 256, 0, stream>>>(images, captions, Gimg, Gcap, imgn, capn,
                                       Ahf, Alf, Bhf, Blf);
  mfma_gemm_kernel<<<1152, 128, 0, stream>>>(Ahf, Alf, Bhf, Blf, C);
  fused_attn_kernel<<<dim3(128, 16), 256, 0, stream>>>(C, Gimg, Gcap, imgn, capn, out);
}